// Round 1
// baseline (710.900 us; speedup 1.0000x reference)
//
#include <hip/hip_runtime.h>
#include <hip/hip_bf16.h>
#include <cstdint>

// Problem dims
#define TSEQ 2048
#define NB   2
#define NH   16
#define EDIM 1024
#define DDIM 64
#define VOC  32000
#define MROWS (NB*TSEQ)   // 4096
#define QKVN  (3*EDIM)    // 3072

typedef _Float16 f16x8 __attribute__((ext_vector_type(8)));
typedef float    f32x4 __attribute__((ext_vector_type(4)));
typedef unsigned short u16x4v __attribute__((ext_vector_type(4)));
typedef unsigned short u16x8v __attribute__((ext_vector_type(8)));

__device__ __forceinline__ unsigned short f2h_bits(float v) {
  return __builtin_bit_cast(unsigned short, (_Float16)v);
}

// async global->LDS, 16B per lane. LDS dest must be wave-uniform base; lane i
// writes bytes [16*i, 16*i+16).
__device__ __forceinline__ void gload_lds16(const void* g, void* l) {
  __builtin_amdgcn_global_load_lds((__attribute__((address_space(1))) void*)(g),
                                   (__attribute__((address_space(3))) void*)(l),
                                   16, 0, 0);
}

// ---------------- embedding: x[row,e] = tok_emb[X[row],e] + pos_emb[row%T,e] (f16 out)
__global__ __launch_bounds__(256) void embed_kernel(
    const int* __restrict__ X, const float* __restrict__ tokE,
    const float* __restrict__ posE, unsigned short* __restrict__ x) {
  int g = blockIdx.x * 256 + threadIdx.x;
  int row = g >> 7;            // 128 threads per row of 1024
  int e8  = (g & 127) * 8;
  int tk  = X[row];
  int tp  = row & (TSEQ - 1);
  const float4* ta = reinterpret_cast<const float4*>(&tokE[(size_t)tk * EDIM + e8]);
  const float4* pa = reinterpret_cast<const float4*>(&posE[(size_t)tp * EDIM + e8]);
  float4 a0 = ta[0], a1 = ta[1], p0 = pa[0], p1 = pa[1];
  u16x8v o;
  o[0] = f2h_bits(a0.x + p0.x); o[1] = f2h_bits(a0.y + p0.y);
  o[2] = f2h_bits(a0.z + p0.z); o[3] = f2h_bits(a0.w + p0.w);
  o[4] = f2h_bits(a1.x + p1.x); o[5] = f2h_bits(a1.y + p1.y);
  o[6] = f2h_bits(a1.z + p1.z); o[7] = f2h_bits(a1.w + p1.w);
  *reinterpret_cast<u16x8v*>(&x[(size_t)row * EDIM + e8]) = o;
}

// ---------------- W{q,k,v}[h,e,d] (f32) -> Wt[n=mat*1024+h*64+d][e] (f16)
__global__ __launch_bounds__(256) void trans_qkvw(
    const float* __restrict__ Wq, const float* __restrict__ Wk,
    const float* __restrict__ Wv, unsigned short* __restrict__ Wt) {
  __shared__ float ts[64][65];
  int bid = blockIdx.x;          // 3*16*16 = 768
  int mat = bid >> 8;
  int h   = (bid >> 4) & 15;
  int et  = bid & 15;
  const float* src = (mat == 0 ? Wq : (mat == 1 ? Wk : Wv)) + (size_t)h * EDIM * DDIM;
  int t = threadIdx.x;
  int rr = t >> 4, c4 = (t & 15) * 4;
#pragma unroll
  for (int p = 0; p < 4; ++p) {
    int r = p * 16 + rr;  // e within tile
    float4 v = *reinterpret_cast<const float4*>(&src[(size_t)(et * 64 + r) * DDIM + c4]);
    ts[r][c4 + 0] = v.x; ts[r][c4 + 1] = v.y; ts[r][c4 + 2] = v.z; ts[r][c4 + 3] = v.w;
  }
  __syncthreads();
#pragma unroll
  for (int p = 0; p < 4; ++p) {
    int dr = p * 16 + rr;  // d
    u16x4v o;
#pragma unroll
    for (int j = 0; j < 4; ++j) o[j] = f2h_bits(ts[c4 + j][dr]);
    *reinterpret_cast<u16x4v*>(&Wt[((size_t)(mat * EDIM + h * 64 + dr)) * EDIM + et * 64 + c4]) = o;
  }
}

// ---------------- lm_W[e,v] (f32) -> lm_Wt[v,e] (f16)
__global__ __launch_bounds__(256) void trans_lmw(
    const float* __restrict__ W, unsigned short* __restrict__ Wt) {
  __shared__ float ts[64][65];
  int bid = blockIdx.x;        // 500 * 16 = 8000
  int vt = bid / 16, et = bid % 16;
  int t = threadIdx.x;
  int rr = t >> 4, c4 = (t & 15) * 4;
#pragma unroll
  for (int p = 0; p < 4; ++p) {
    int r = p * 16 + rr;  // e within tile
    float4 v = *reinterpret_cast<const float4*>(&W[(size_t)(et * 64 + r) * VOC + vt * 64 + c4]);
    ts[r][c4 + 0] = v.x; ts[r][c4 + 1] = v.y; ts[r][c4 + 2] = v.z; ts[r][c4 + 3] = v.w;
  }
  __syncthreads();
#pragma unroll
  for (int p = 0; p < 4; ++p) {
    int vr = p * 16 + rr;  // v within tile
    u16x4v o;
#pragma unroll
    for (int j = 0; j < 4; ++j) o[j] = f2h_bits(ts[c4 + j][vr]);
    *reinterpret_cast<u16x4v*>(&Wt[(size_t)(vt * 64 + vr) * EDIM + et * 64 + c4]) = o;
  }
}

// ---------------- GEMM: A[M,K] f16, Bt[N,K] f16 -> C[M,N] (f32+bias or f16)
// m97 structure: 128x128 tile, 4 waves (2x2), 4x4 16x16x32 frags, BK=32,
// global_load_lds staging into linear LDS, 2 barriers per K-step.
template <bool F32OUT, bool BIAS>
__global__ __launch_bounds__(256) void gemm_bt(
    const unsigned short* __restrict__ A, const unsigned short* __restrict__ Bt,
    float* __restrict__ Cf, unsigned short* __restrict__ Ch,
    const float* __restrict__ bias, int N, int K) {
  __shared__ unsigned short As[128 * 32];
  __shared__ unsigned short Bs[128 * 32];
  const int tid = threadIdx.x;
  const int w = tid >> 6, l = tid & 63;
  const int wr = w >> 1, wc = w & 1;
  const int l15 = l & 15, lhi = l >> 4;
  const int m0 = blockIdx.y * 128, n0 = blockIdx.x * 128;
  const int srow = l >> 2, scol = (l & 3) * 8;
  const unsigned short* Ag = A  + (size_t)(m0 + w * 16 + srow) * K + scol;
  const unsigned short* Bg = Bt + (size_t)(n0 + w * 16 + srow) * K + scol;
  f32x4 acc[4][4] = {};
  for (int kt = 0; kt < K; kt += 32) {
    gload_lds16(Ag + kt,                 &As[(w * 16) * 32]);
    gload_lds16(Ag + (size_t)64 * K + kt, &As[(64 + w * 16) * 32]);
    gload_lds16(Bg + kt,                 &Bs[(w * 16) * 32]);
    gload_lds16(Bg + (size_t)64 * K + kt, &Bs[(64 + w * 16) * 32]);
    __syncthreads();
    f16x8 af[4], bfr[4];
#pragma unroll
    for (int mi = 0; mi < 4; ++mi)
      af[mi] = *reinterpret_cast<const f16x8*>(&As[(wr * 64 + mi * 16 + l15) * 32 + lhi * 8]);
#pragma unroll
    for (int ni = 0; ni < 4; ++ni)
      bfr[ni] = *reinterpret_cast<const f16x8*>(&Bs[(wc * 64 + ni * 16 + l15) * 32 + lhi * 8]);
#pragma unroll
    for (int mi = 0; mi < 4; ++mi)
#pragma unroll
      for (int ni = 0; ni < 4; ++ni)
        acc[mi][ni] = __builtin_amdgcn_mfma_f32_16x16x32_f16(af[mi], bfr[ni], acc[mi][ni], 0, 0, 0);
    __syncthreads();
  }
  // epilogue; C/D frag layout: col = lane&15, row = (lane>>4)*4 + r
#pragma unroll
  for (int ni = 0; ni < 4; ++ni) {
    const int col = n0 + wc * 64 + ni * 16 + l15;
    float bv = BIAS ? bias[col] : 0.0f;
#pragma unroll
    for (int mi = 0; mi < 4; ++mi) {
#pragma unroll
      for (int r = 0; r < 4; ++r) {
        const size_t row = (size_t)m0 + wr * 64 + mi * 16 + lhi * 4 + r;
        float v = acc[mi][ni][r] + bv;
        if constexpr (F32OUT) Cf[row * (size_t)N + col] = v;
        else                  Ch[row * (size_t)N + col] = f2h_bits(v);
      }
    }
  }
}

// ---------------- causal flash attention
// qkv[M, 3072]: cols [0,1024)=Q(h,d), [1024,2048)=K, [2048,3072)=V  (f16)
// one block = one (b,h,qtile of 64 rows); 4 waves x 16 q-rows; KV tiles of 64.
__global__ __launch_bounds__(256) void attn_kernel(
    const unsigned short* __restrict__ qkv, unsigned short* __restrict__ out) {
  __shared__ unsigned short Vt[64 * 72];       // V^T tile: [d][kv], padded
  __shared__ unsigned short Pl[4 * 16 * 72];   // per-wave P tile: [qrow][kv]
  const int bid = blockIdx.x;
  const int qt = bid & 31, bh = bid >> 5;
  const int b = bh >> 4, h = bh & 15;
  const int tid = threadIdx.x, w = tid >> 6, l = tid & 63;
  const int l15 = l & 15, lhi = l >> 4;
  const int q0 = qt * 64;
  const size_t RS = QKVN;  // row stride in elements
  const unsigned short* qbase = qkv + (size_t)b * TSEQ * RS + h * 64;
  const unsigned short* kbase = qbase + EDIM;
  const unsigned short* vbase = qbase + 2 * EDIM;

  // Q fragments stay in registers for the whole kernel
  f16x8 qa[2];
  {
    const int qrow = q0 + w * 16 + l15;
#pragma unroll
    for (int ks = 0; ks < 2; ++ks)
      qa[ks] = *reinterpret_cast<const f16x8*>(qbase + (size_t)qrow * RS + ks * 32 + lhi * 8);
  }
  float m_run[4], l_run[4];
  f32x4 o[4] = {};
#pragma unroll
  for (int r = 0; r < 4; ++r) { m_run[r] = -__builtin_inff(); l_run[r] = 0.f; }
  const int myrow = q0 + w * 16 + lhi * 4;
  unsigned short* pl = &Pl[w * 16 * 72];

  for (int kt = 0; kt <= qt; ++kt) {
    const int kv0 = kt * 64;
    __syncthreads();  // previous iter's Vt reads done
    {   // stage V tile transposed: Vt[d][kv]
      const int r = tid >> 3, c8 = (tid & 7) * 8;
#pragma unroll
      for (int p = 0; p < 2; ++p) {
        const int rr = r + p * 32;
        u16x8v v = *reinterpret_cast<const u16x8v*>(vbase + (size_t)(kv0 + rr) * RS + c8);
#pragma unroll
        for (int j = 0; j < 8; ++j) Vt[(c8 + j) * 72 + rr] = v[j];
      }
    }
    __syncthreads();
    // S = Q K^T  (B-operand = K rows read straight from L2)
    f32x4 s[4];
#pragma unroll
    for (int ct = 0; ct < 4; ++ct) {
      f32x4 acc = {};
#pragma unroll
      for (int ks = 0; ks < 2; ++ks) {
        f16x8 kb = *reinterpret_cast<const f16x8*>(
            kbase + (size_t)(kv0 + ct * 16 + l15) * RS + ks * 32 + lhi * 8);
        acc = __builtin_amdgcn_mfma_f32_16x16x32_f16(qa[ks], kb, acc, 0, 0, 0);
      }
      s[ct] = acc;
    }
    // scale + causal mask
#pragma unroll
    for (int ct = 0; ct < 4; ++ct) {
      const int col = kv0 + ct * 16 + l15;
#pragma unroll
      for (int r = 0; r < 4; ++r) {
        float v = s[ct][r] * 0.125f;
        if (col > myrow + r) v = -__builtin_inff();
        s[ct][r] = v;
      }
    }
    // online softmax (rows live across a 16-lane group)
    float alpha[4];
#pragma unroll
    for (int r = 0; r < 4; ++r) {
      float mx = fmaxf(fmaxf(s[0][r], s[1][r]), fmaxf(s[2][r], s[3][r]));
      mx = fmaxf(mx, __shfl_xor(mx, 1)); mx = fmaxf(mx, __shfl_xor(mx, 2));
      mx = fmaxf(mx, __shfl_xor(mx, 4)); mx = fmaxf(mx, __shfl_xor(mx, 8));
      const float mn = fmaxf(m_run[r], mx);
      alpha[r] = __expf(m_run[r] - mn);   // exp(-inf)=0 on first tile
      m_run[r] = mn;
    }
    float rs[4] = {0.f, 0.f, 0.f, 0.f};
#pragma unroll
    for (int ct = 0; ct < 4; ++ct)
#pragma unroll
      for (int r = 0; r < 4; ++r) {
        const float p = __expf(s[ct][r] - m_run[r]);   // masked -> 0
        s[ct][r] = p;
        rs[r] += p;
      }
#pragma unroll
    for (int r = 0; r < 4; ++r) {
      float t = rs[r];
      t += __shfl_xor(t, 1); t += __shfl_xor(t, 2);
      t += __shfl_xor(t, 4); t += __shfl_xor(t, 8);
      l_run[r] = l_run[r] * alpha[r] + t;
    }
#pragma unroll
    for (int ct = 0; ct < 4; ++ct)
#pragma unroll
      for (int r = 0; r < 4; ++r) o[ct][r] *= alpha[r];
    // P (C-layout) -> LDS -> A-layout fragments
#pragma unroll
    for (int ct = 0; ct < 4; ++ct)
#pragma unroll
      for (int r = 0; r < 4; ++r)
        pl[(lhi * 4 + r) * 72 + ct * 16 + l15] = f2h_bits(s[ct][r]);
    // O += P V
#pragma unroll
    for (int ks = 0; ks < 2; ++ks) {
      f16x8 pa = *reinterpret_cast<const f16x8*>(&pl[l15 * 72 + ks * 32 + lhi * 8]);
#pragma unroll
      for (int ct = 0; ct < 4; ++ct) {
        f16x8 vb = *reinterpret_cast<const f16x8*>(&Vt[(ct * 16 + l15) * 72 + ks * 32 + lhi * 8]);
        o[ct] = __builtin_amdgcn_mfma_f32_16x16x32_f16(pa, vb, o[ct], 0, 0, 0);
      }
    }
  }
  // epilogue: out[b*T + row, h*64 + d] = o / l
  unsigned short* obase = out + ((size_t)(b * TSEQ + q0 + w * 16)) * EDIM + h * 64;
#pragma unroll
  for (int ct = 0; ct < 4; ++ct)
#pragma unroll
    for (int r = 0; r < 4; ++r) {
      const float v = o[ct][r] / l_run[r];
      obase[(size_t)(lhi * 4 + r) * EDIM + ct * 16 + l15] = f2h_bits(v);
    }
}

extern "C" void kernel_launch(void* const* d_in, const int* in_sizes, int n_in,
                              void* d_out, int out_size, void* d_ws, size_t ws_size,
                              hipStream_t stream) {
  const int*   X    = (const int*)d_in[0];
  const float* tokE = (const float*)d_in[1];
  const float* posE = (const float*)d_in[2];
  const float* Wq   = (const float*)d_in[3];
  const float* Wk   = (const float*)d_in[4];
  const float* Wv   = (const float*)d_in[5];
  const float* lmW  = (const float*)d_in[6];
  const float* lmb  = (const float*)d_in[7];
  float* out = (float*)d_out;

  // workspace layout (f16 elements); total = 113,770,496 bytes (~108.5 MB)
  unsigned short* ws   = (unsigned short*)d_ws;
  unsigned short* x    = ws;                              // [4096,1024]
  unsigned short* att  = x    + (size_t)MROWS * EDIM;     // [4096,1024]
  unsigned short* wqkv = att  + (size_t)MROWS * EDIM;     // [3072,1024]
  unsigned short* qkv  = wqkv + (size_t)QKVN * EDIM;      // [4096,3072]
  unsigned short* lmWt = qkv  + (size_t)MROWS * QKVN;     // [32000,1024]

  embed_kernel<<<(MROWS * EDIM / 8) / 256, 256, 0, stream>>>(X, tokE, posE, x);
  trans_qkvw<<<3 * NH * (EDIM / 64), 256, 0, stream>>>(Wq, Wk, Wv, wqkv);
  trans_lmw<<<(VOC / 64) * (EDIM / 64), 256, 0, stream>>>(lmW, lmWt);
  gemm_bt<false, false><<<dim3(QKVN / 128, MROWS / 128), 256, 0, stream>>>(
      x, wqkv, nullptr, qkv, nullptr, QKVN, EDIM);
  attn_kernel<<<NB * NH * (TSEQ / 64), 256, 0, stream>>>(qkv, att);
  gemm_bt<true, true><<<dim3(VOC / 128, MROWS / 128), 256, 0, stream>>>(
      att, lmWt, out, nullptr, lmb, VOC, EDIM);
}

// Round 2
// 658.921 us; speedup vs baseline: 1.0789x; 1.0789x over previous
//
#include <hip/hip_runtime.h>
#include <hip/hip_bf16.h>
#include <cstdint>

// Problem dims
#define TSEQ 2048
#define NB   2
#define NH   16
#define EDIM 1024
#define DDIM 64
#define VOC  32000
#define MROWS (NB*TSEQ)   // 4096
#define QKVN  (3*EDIM)    // 3072

typedef _Float16 f16x8 __attribute__((ext_vector_type(8)));
typedef float    f32x4 __attribute__((ext_vector_type(4)));
typedef unsigned short u16x4v __attribute__((ext_vector_type(4)));
typedef unsigned short u16x8v __attribute__((ext_vector_type(8)));

__device__ __forceinline__ unsigned short f2h_bits(float v) {
  return __builtin_bit_cast(unsigned short, (_Float16)v);
}

// async global->LDS, 16B per lane. LDS dest is wave-uniform base; lane i
// writes bytes [16*i, 16*i+16). Per-lane global source address is free.
__device__ __forceinline__ void gload_lds16(const void* g, void* l) {
  __builtin_amdgcn_global_load_lds((__attribute__((address_space(1))) void*)(g),
                                   (__attribute__((address_space(3))) void*)(l),
                                   16, 0, 0);
}

// ---------------- embedding: x[row,e] = tok_emb[X[row],e] + pos_emb[row%T,e] (f16 out)
__global__ __launch_bounds__(256) void embed_kernel(
    const int* __restrict__ X, const float* __restrict__ tokE,
    const float* __restrict__ posE, unsigned short* __restrict__ x) {
  int g = blockIdx.x * 256 + threadIdx.x;
  int row = g >> 7;            // 128 threads per row of 1024
  int e8  = (g & 127) * 8;
  int tk  = X[row];
  int tp  = row & (TSEQ - 1);
  const float4* ta = reinterpret_cast<const float4*>(&tokE[(size_t)tk * EDIM + e8]);
  const float4* pa = reinterpret_cast<const float4*>(&posE[(size_t)tp * EDIM + e8]);
  float4 a0 = ta[0], a1 = ta[1], p0 = pa[0], p1 = pa[1];
  u16x8v o;
  o[0] = f2h_bits(a0.x + p0.x); o[1] = f2h_bits(a0.y + p0.y);
  o[2] = f2h_bits(a0.z + p0.z); o[3] = f2h_bits(a0.w + p0.w);
  o[4] = f2h_bits(a1.x + p1.x); o[5] = f2h_bits(a1.y + p1.y);
  o[6] = f2h_bits(a1.z + p1.z); o[7] = f2h_bits(a1.w + p1.w);
  *reinterpret_cast<u16x8v*>(&x[(size_t)row * EDIM + e8]) = o;
}

// ---------------- W{q,k,v}[h,e,d] (f32) -> Wt[n=mat*1024+h*64+d][e] (f16)
__global__ __launch_bounds__(256) void trans_qkvw(
    const float* __restrict__ Wq, const float* __restrict__ Wk,
    const float* __restrict__ Wv, unsigned short* __restrict__ Wt) {
  __shared__ float ts[64][65];
  int bid = blockIdx.x;          // 3*16*16 = 768
  int mat = bid >> 8;
  int h   = (bid >> 4) & 15;
  int et  = bid & 15;
  const float* src = (mat == 0 ? Wq : (mat == 1 ? Wk : Wv)) + (size_t)h * EDIM * DDIM;
  int t = threadIdx.x;
  int rr = t >> 4, c4 = (t & 15) * 4;
#pragma unroll
  for (int p = 0; p < 4; ++p) {
    int r = p * 16 + rr;  // e within tile
    float4 v = *reinterpret_cast<const float4*>(&src[(size_t)(et * 64 + r) * DDIM + c4]);
    ts[r][c4 + 0] = v.x; ts[r][c4 + 1] = v.y; ts[r][c4 + 2] = v.z; ts[r][c4 + 3] = v.w;
  }
  __syncthreads();
#pragma unroll
  for (int p = 0; p < 4; ++p) {
    int dr = p * 16 + rr;  // d
    u16x4v o;
#pragma unroll
    for (int j = 0; j < 4; ++j) o[j] = f2h_bits(ts[c4 + j][dr]);
    *reinterpret_cast<u16x4v*>(&Wt[((size_t)(mat * EDIM + h * 64 + dr)) * EDIM + et * 64 + c4]) = o;
  }
}

// ---------------- lm_W[e,v] (f32) -> lm_Wt[v,e] (f16)
__global__ __launch_bounds__(256) void trans_lmw(
    const float* __restrict__ W, unsigned short* __restrict__ Wt) {
  __shared__ float ts[64][65];
  int bid = blockIdx.x;        // 500 * 16 = 8000
  int vt = bid / 16, et = bid % 16;
  int t = threadIdx.x;
  int rr = t >> 4, c4 = (t & 15) * 4;
#pragma unroll
  for (int p = 0; p < 4; ++p) {
    int r = p * 16 + rr;  // e within tile
    float4 v = *reinterpret_cast<const float4*>(&W[(size_t)(et * 64 + r) * VOC + vt * 64 + c4]);
    ts[r][c4 + 0] = v.x; ts[r][c4 + 1] = v.y; ts[r][c4 + 2] = v.z; ts[r][c4 + 3] = v.w;
  }
  __syncthreads();
#pragma unroll
  for (int p = 0; p < 4; ++p) {
    int vr = p * 16 + rr;  // v within tile
    u16x4v o;
#pragma unroll
    for (int j = 0; j < 4; ++j) o[j] = f2h_bits(ts[c4 + j][vr]);
    *reinterpret_cast<u16x4v*>(&Wt[(size_t)(vt * 64 + vr) * EDIM + et * 64 + c4]) = o;
  }
}

// ---------------- 256x256 deep-pipelined GEMM: A[M,K] f16, Bt[N,K] f16 -> C[M,N]
// 8 waves (2M x 4N), BK=64, 128 KiB LDS as 2 bufs x {A,B} x {k-half} regions
// of [256 rows][32 cols] f16 (16 KB each). 4 phases per K-tile, 16 MFMA each.
// Counted s_waitcnt vmcnt(4) at the two barriers per K-tile: 4 loads stay in
// flight across every barrier (never drained to 0 in the main loop).
// Bank-conflict fix: chunk-XOR swizzle c' = c ^ ((row>>1)&3) on 16B chunks,
// applied to BOTH the pre-swizzled global_load_lds source and the ds_read
// address (involution). M assumed 4096 (16 M-blocks); nwg % 8 == 0.
template <bool F32OUT, bool BIAS>
__global__ __launch_bounds__(512, 2) void gemm256(
    const unsigned short* __restrict__ A, const unsigned short* __restrict__ Bt,
    float* __restrict__ Cf, unsigned short* __restrict__ Ch,
    const float* __restrict__ bias, int N, int K) {
  __shared__ unsigned short lds[65536];   // 128 KiB
  const int tid = threadIdx.x;
  const int w = tid >> 6, l = tid & 63;
  const int wr = w >> 2, wc = w & 3;      // 2 x 4 wave grid
  const int l15 = l & 15, lhi = l >> 4;

  // XCD-bijective block swizzle + M-fastest ordering (nby = 4096/256 = 16)
  const int nwg = gridDim.x;
  const int orig = blockIdx.x;
  const int swz = (orig & 7) * (nwg >> 3) + (orig >> 3);
  const int bx = swz >> 4;            // N-block
  const int by = swz & 15;            // M-block (fastest within XCD chunk)
  const int m0 = by * 256, n0 = bx * 256;

  // ds_read swizzled chunk (16B units within a 64B region row)
  const int swzc = lhi ^ ((l15 >> 1) & 3);
  // per-thread ds_read element bases: + frag*512 + ks*8192 + buf*32768 (+16384 for B)
  const int aOff = (wr * 128 + l15) * 32 + swzc * 8;
  const int bOff = 16384 + (wc * 64 + l15) * 32 + swzc * 8;

  // staging: per region (16 KB = 2 calls x 8 waves x 1 KB);
  // lane -> (row, chunk): row = +(l>>2), LDS chunk pos = l&3 holds global
  // chunk (l&3) ^ ((l>>3)&3)  [= (l&3) ^ ((row>>1)&3)]
  const int sr = l >> 2;
  const int sc = (l & 3) ^ ((l >> 3) & 3);
  const unsigned short* PA = A  + (size_t)(m0 + w * 16 + sr) * K + sc * 8;
  const unsigned short* PB = Bt + (size_t)(n0 + w * 16 + sr) * K + sc * 8;
  const int dOff = w * 512;  // wave-uniform dest (16 rows * 32 els)

#define STAGE(mat, Pm, ks, ts, bufD) do {                                     \
    gload_lds16(Pm + (size_t)(ts) * 64 + (ks) * 32,                           \
                &lds[(bufD) * 32768 + (mat) * 16384 + (ks) * 8192 + dOff]);   \
    gload_lds16(Pm + (size_t)128 * K + (size_t)(ts) * 64 + (ks) * 32,         \
                &lds[(bufD) * 32768 + (mat) * 16384 + (ks) * 8192 + 4096 + dOff]); \
  } while (0)

  f32x4 acc[8][4] = {};
  // prologue: stage tile 0 into buf 0; issue order [Ak0,Bk0,Ak1,Bk1]
  STAGE(0, PA, 0, 0, 0);
  STAGE(1, PB, 0, 0, 0);
  STAGE(0, PA, 1, 0, 0);
  STAGE(1, PB, 1, 0, 0);
  asm volatile("s_waitcnt vmcnt(4)" ::: "memory");   // Ak0,Bk0 landed
  __builtin_amdgcn_sched_barrier(0);
  __builtin_amdgcn_s_barrier();

  const int NT = K >> 6;
  for (int t = 0; t < NT; ++t) {
    const int bufE = (t & 1) * 32768;      // current buffer (elements)
    const int dstB = (t & 1) ^ 1;          // staging buffer
    const int ts = (t + 1 < NT) ? (t + 1) : (NT - 1);  // clamp keeps vmcnt symmetric
    f16x8 af[4], bf[4];
    // ---------- ks = 0, phase 1: A rows half 0 ----------
    {
      const unsigned short* pa = &lds[bufE + aOff];
      const unsigned short* pb = &lds[bufE + bOff];
#pragma unroll
      for (int q = 0; q < 4; ++q) af[q] = *reinterpret_cast<const f16x8*>(pa + q * 512);
#pragma unroll
      for (int q = 0; q < 4; ++q) bf[q] = *reinterpret_cast<const f16x8*>(pb + q * 512);
      STAGE(0, PA, 0, ts, dstB);
      asm volatile("s_waitcnt lgkmcnt(0)" ::: "memory");
      __builtin_amdgcn_sched_barrier(0);
      __builtin_amdgcn_s_setprio(1);
#pragma unroll
      for (int mi = 0; mi < 4; ++mi)
#pragma unroll
        for (int ni = 0; ni < 4; ++ni)
          acc[mi][ni] = __builtin_amdgcn_mfma_f32_16x16x32_f16(af[mi], bf[ni], acc[mi][ni], 0, 0, 0);
      __builtin_amdgcn_s_setprio(0);
    }
    // ---------- ks = 0, phase 2: A rows half 1 (reuse bf) ----------
    {
      const unsigned short* pa = &lds[bufE + aOff + 2048];
#pragma unroll
      for (int q = 0; q < 4; ++q) af[q] = *reinterpret_cast<const f16x8*>(pa + q * 512);
      STAGE(1, PB, 0, ts, dstB);
      asm volatile("s_waitcnt lgkmcnt(0)" ::: "memory");
      __builtin_amdgcn_sched_barrier(0);
      __builtin_amdgcn_s_setprio(1);
#pragma unroll
      for (int mi = 0; mi < 4; ++mi)
#pragma unroll
        for (int ni = 0; ni < 4; ++ni)
          acc[4 + mi][ni] = __builtin_amdgcn_mfma_f32_16x16x32_f16(af[mi], bf[ni], acc[4 + mi][ni], 0, 0, 0);
      __builtin_amdgcn_s_setprio(0);
    }
    // barrier 1: need Ak1(t),Bk1(t) (the 4 oldest outstanding); keep 4 in flight
    asm volatile("s_waitcnt vmcnt(4)" ::: "memory");
    __builtin_amdgcn_sched_barrier(0);
    __builtin_amdgcn_s_barrier();
    // ---------- ks = 1, phase 3: A rows half 0 ----------
    {
      const unsigned short* pa = &lds[bufE + aOff + 8192];
      const unsigned short* pb = &lds[bufE + bOff + 8192];
#pragma unroll
      for (int q = 0; q < 4; ++q) af[q] = *reinterpret_cast<const f16x8*>(pa + q * 512);
#pragma unroll
      for (int q = 0; q < 4; ++q) bf[q] = *reinterpret_cast<const f16x8*>(pb + q * 512);
      STAGE(0, PA, 1, ts, dstB);
      asm volatile("s_waitcnt lgkmcnt(0)" ::: "memory");
      __builtin_amdgcn_sched_barrier(0);
      __builtin_amdgcn_s_setprio(1);
#pragma unroll
      for (int mi = 0; mi < 4; ++mi)
#pragma unroll
        for (int ni = 0; ni < 4; ++ni)
          acc[mi][ni] = __builtin_amdgcn_mfma_f32_16x16x32_f16(af[mi], bf[ni], acc[mi][ni], 0, 0, 0);
      __builtin_amdgcn_s_setprio(0);
    }
    // ---------- ks = 1, phase 4: A rows half 1 (reuse bf) ----------
    {
      const unsigned short* pa = &lds[bufE + aOff + 8192 + 2048];
#pragma unroll
      for (int q = 0; q < 4; ++q) af[q] = *reinterpret_cast<const f16x8*>(pa + q * 512);
      STAGE(1, PB, 1, ts, dstB);
      asm volatile("s_waitcnt lgkmcnt(0)" ::: "memory");
      __builtin_amdgcn_sched_barrier(0);
      __builtin_amdgcn_s_setprio(1);
#pragma unroll
      for (int mi = 0; mi < 4; ++mi)
#pragma unroll
        for (int ni = 0; ni < 4; ++ni)
          acc[4 + mi][ni] = __builtin_amdgcn_mfma_f32_16x16x32_f16(af[mi], bf[ni], acc[4 + mi][ni], 0, 0, 0);
      __builtin_amdgcn_s_setprio(0);
    }
    // barrier 2: need Ak0(t+1),Bk0(t+1); Ak1(t+1),Bk1(t+1) stay in flight
    asm volatile("s_waitcnt vmcnt(4)" ::: "memory");
    __builtin_amdgcn_sched_barrier(0);
    __builtin_amdgcn_s_barrier();
  }
#undef STAGE
  asm volatile("s_waitcnt vmcnt(0)" ::: "memory");  // drain dummy tail loads

  // epilogue; C/D frag layout: col = lane&15, row = (lane>>4)*4 + r
#pragma unroll
  for (int ni = 0; ni < 4; ++ni) {
    const int col = n0 + wc * 64 + ni * 16 + l15;
    float bv = BIAS ? bias[col] : 0.0f;
#pragma unroll
    for (int mi = 0; mi < 8; ++mi) {
#pragma unroll
      for (int r = 0; r < 4; ++r) {
        const size_t row = (size_t)m0 + wr * 128 + mi * 16 + lhi * 4 + r;
        float v = acc[mi][ni][r] + bv;
        if constexpr (F32OUT) Cf[row * (size_t)N + col] = v;
        else                  Ch[row * (size_t)N + col] = f2h_bits(v);
      }
    }
  }
}

// ---------------- causal flash attention
// qkv[M, 3072]: cols [0,1024)=Q(h,d), [1024,2048)=K, [2048,3072)=V  (f16)
// one block = one (b,h,qtile of 64 rows); 4 waves x 16 q-rows; KV tiles of 64.
__global__ __launch_bounds__(256) void attn_kernel(
    const unsigned short* __restrict__ qkv, unsigned short* __restrict__ out) {
  __shared__ unsigned short Vt[64 * 72];       // V^T tile: [d][kv], padded
  __shared__ unsigned short Pl[4 * 16 * 72];   // per-wave P tile: [qrow][kv]
  const int bid = blockIdx.x;
  const int qt = bid & 31, bh = bid >> 5;
  const int b = bh >> 4, h = bh & 15;
  const int tid = threadIdx.x, w = tid >> 6, l = tid & 63;
  const int l15 = l & 15, lhi = l >> 4;
  const int q0 = qt * 64;
  const size_t RS = QKVN;  // row stride in elements
  const unsigned short* qbase = qkv + (size_t)b * TSEQ * RS + h * 64;
  const unsigned short* kbase = qbase + EDIM;
  const unsigned short* vbase = qbase + 2 * EDIM;

  // Q fragments stay in registers for the whole kernel
  f16x8 qa[2];
  {
    const int qrow = q0 + w * 16 + l15;
#pragma unroll
    for (int ks = 0; ks < 2; ++ks)
      qa[ks] = *reinterpret_cast<const f16x8*>(qbase + (size_t)qrow * RS + ks * 32 + lhi * 8);
  }
  float m_run[4], l_run[4];
  f32x4 o[4] = {};
#pragma unroll
  for (int r = 0; r < 4; ++r) { m_run[r] = -__builtin_inff(); l_run[r] = 0.f; }
  const int myrow = q0 + w * 16 + lhi * 4;
  unsigned short* pl = &Pl[w * 16 * 72];

  for (int kt = 0; kt <= qt; ++kt) {
    const int kv0 = kt * 64;
    __syncthreads();  // previous iter's Vt reads done
    {   // stage V tile transposed: Vt[d][kv]
      const int r = tid >> 3, c8 = (tid & 7) * 8;
#pragma unroll
      for (int p = 0; p < 2; ++p) {
        const int rr = r + p * 32;
        u16x8v v = *reinterpret_cast<const u16x8v*>(vbase + (size_t)(kv0 + rr) * RS + c8);
#pragma unroll
        for (int j = 0; j < 8; ++j) Vt[(c8 + j) * 72 + rr] = v[j];
      }
    }
    __syncthreads();
    // S = Q K^T  (B-operand = K rows read straight from L2)
    f32x4 s[4];
#pragma unroll
    for (int ct = 0; ct < 4; ++ct) {
      f32x4 acc = {};
#pragma unroll
      for (int ks = 0; ks < 2; ++ks) {
        f16x8 kb = *reinterpret_cast<const f16x8*>(
            kbase + (size_t)(kv0 + ct * 16 + l15) * RS + ks * 32 + lhi * 8);
        acc = __builtin_amdgcn_mfma_f32_16x16x32_f16(qa[ks], kb, acc, 0, 0, 0);
      }
      s[ct] = acc;
    }
    // scale + causal mask
#pragma unroll
    for (int ct = 0; ct < 4; ++ct) {
      const int col = kv0 + ct * 16 + l15;
#pragma unroll
      for (int r = 0; r < 4; ++r) {
        float v = s[ct][r] * 0.125f;
        if (col > myrow + r) v = -__builtin_inff();
        s[ct][r] = v;
      }
    }
    // online softmax (rows live across a 16-lane group)
    float alpha[4];
#pragma unroll
    for (int r = 0; r < 4; ++r) {
      float mx = fmaxf(fmaxf(s[0][r], s[1][r]), fmaxf(s[2][r], s[3][r]));
      mx = fmaxf(mx, __shfl_xor(mx, 1)); mx = fmaxf(mx, __shfl_xor(mx, 2));
      mx = fmaxf(mx, __shfl_xor(mx, 4)); mx = fmaxf(mx, __shfl_xor(mx, 8));
      const float mn = fmaxf(m_run[r], mx);
      alpha[r] = __expf(m_run[r] - mn);   // exp(-inf)=0 on first tile
      m_run[r] = mn;
    }
    float rs[4] = {0.f, 0.f, 0.f, 0.f};
#pragma unroll
    for (int ct = 0; ct < 4; ++ct)
#pragma unroll
      for (int r = 0; r < 4; ++r) {
        const float p = __expf(s[ct][r] - m_run[r]);   // masked -> 0
        s[ct][r] = p;
        rs[r] += p;
      }
#pragma unroll
    for (int r = 0; r < 4; ++r) {
      float t = rs[r];
      t += __shfl_xor(t, 1); t += __shfl_xor(t, 2);
      t += __shfl_xor(t, 4); t += __shfl_xor(t, 8);
      l_run[r] = l_run[r] * alpha[r] + t;
    }
#pragma unroll
    for (int ct = 0; ct < 4; ++ct)
#pragma unroll
      for (int r = 0; r < 4; ++r) o[ct][r] *= alpha[r];
    // P (C-layout) -> LDS -> A-layout fragments
#pragma unroll
    for (int ct = 0; ct < 4; ++ct)
#pragma unroll
      for (int r = 0; r < 4; ++r)
        pl[(lhi * 4 + r) * 72 + ct * 16 + l15] = f2h_bits(s[ct][r]);
    // O += P V
#pragma unroll
    for (int ks = 0; ks < 2; ++ks) {
      f16x8 pa = *reinterpret_cast<const f16x8*>(&pl[l15 * 72 + ks * 32 + lhi * 8]);
#pragma unroll
      for (int ct = 0; ct < 4; ++ct) {
        f16x8 vb = *reinterpret_cast<const f16x8*>(&Vt[(ct * 16 + l15) * 72 + ks * 32 + lhi * 8]);
        o[ct] = __builtin_amdgcn_mfma_f32_16x16x32_f16(pa, vb, o[ct], 0, 0, 0);
      }
    }
  }
  // epilogue: out[b*T + row, h*64 + d] = o / l
  unsigned short* obase = out + ((size_t)(b * TSEQ + q0 + w * 16)) * EDIM + h * 64;
#pragma unroll
  for (int ct = 0; ct < 4; ++ct)
#pragma unroll
    for (int r = 0; r < 4; ++r) {
      const float v = o[ct][r] / l_run[r];
      obase[(size_t)(lhi * 4 + r) * EDIM + ct * 16 + l15] = f2h_bits(v);
    }
}

extern "C" void kernel_launch(void* const* d_in, const int* in_sizes, int n_in,
                              void* d_out, int out_size, void* d_ws, size_t ws_size,
                              hipStream_t stream) {
  const int*   X    = (const int*)d_in[0];
  const float* tokE = (const float*)d_in[1];
  const float* posE = (const float*)d_in[2];
  const float* Wq   = (const float*)d_in[3];
  const float* Wk   = (const float*)d_in[4];
  const float* Wv   = (const float*)d_in[5];
  const float* lmW  = (const float*)d_in[6];
  const float* lmb  = (const float*)d_in[7];
  float* out = (float*)d_out;

  // workspace layout (f16 elements); total ~108.5 MB
  unsigned short* ws   = (unsigned short*)d_ws;
  unsigned short* x    = ws;                              // [4096,1024]
  unsigned short* att  = x    + (size_t)MROWS * EDIM;     // [4096,1024]
  unsigned short* wqkv = att  + (size_t)MROWS * EDIM;     // [3072,1024]
  unsigned short* qkv  = wqkv + (size_t)QKVN * EDIM;      // [4096,3072]
  unsigned short* lmWt = qkv  + (size_t)MROWS * QKVN;     // [32000,1024]

  embed_kernel<<<(MROWS * EDIM / 8) / 256, 256, 0, stream>>>(X, tokE, posE, x);
  trans_qkvw<<<3 * NH * (EDIM / 64), 256, 0, stream>>>(Wq, Wk, Wv, wqkv);
  trans_lmw<<<(VOC / 64) * (EDIM / 64), 256, 0, stream>>>(lmW, lmWt);
  // QKV proj: M=4096, N=3072, K=1024 -> 12*16 = 192 blocks (%8==0)
  gemm256<false, false><<<(QKVN / 256) * (MROWS / 256), 512, 0, stream>>>(
      x, wqkv, nullptr, qkv, nullptr, QKVN, EDIM);
  attn_kernel<<<NB * NH * (TSEQ / 64), 256, 0, stream>>>(qkv, att);
  // LM head: M=4096, N=32000, K=1024 -> 125*16 = 2000 blocks (%8==0)
  gemm256<true, true><<<(VOC / 256) * (MROWS / 256), 512, 0, stream>>>(
      att, lmWt, out, nullptr, lmb, VOC, EDIM);
}

// Round 3
// 655.955 us; speedup vs baseline: 1.0838x; 1.0045x over previous
//
#include <hip/hip_runtime.h>
#include <hip/hip_bf16.h>
#include <cstdint>

// Problem dims
#define TSEQ 2048
#define NB   2
#define NH   16
#define EDIM 1024
#define DDIM 64
#define VOC  32000
#define MROWS (NB*TSEQ)   // 4096
#define QKVN  (3*EDIM)    // 3072

typedef _Float16 f16x8 __attribute__((ext_vector_type(8)));
typedef float    f32x4 __attribute__((ext_vector_type(4)));
typedef unsigned short u16x4v __attribute__((ext_vector_type(4)));
typedef unsigned short u16x8v __attribute__((ext_vector_type(8)));

__device__ __forceinline__ unsigned short f2h_bits(float v) {
  return __builtin_bit_cast(unsigned short, (_Float16)v);
}

// async global->LDS, 16B per lane. LDS dest is wave-uniform base; lane i
// writes bytes [16*i, 16*i+16). Per-lane global source address is free.
__device__ __forceinline__ void gload_lds16(const void* g, void* l) {
  __builtin_amdgcn_global_load_lds((__attribute__((address_space(1))) void*)(g),
                                   (__attribute__((address_space(3))) void*)(l),
                                   16, 0, 0);
}

// ---------------- embedding: x[row,e] = tok_emb[X[row],e] + pos_emb[row%T,e] (f16 out)
__global__ __launch_bounds__(256) void embed_kernel(
    const int* __restrict__ X, const float* __restrict__ tokE,
    const float* __restrict__ posE, unsigned short* __restrict__ x) {
  int g = blockIdx.x * 256 + threadIdx.x;
  int row = g >> 7;            // 128 threads per row of 1024
  int e8  = (g & 127) * 8;
  int tk  = X[row];
  int tp  = row & (TSEQ - 1);
  const float4* ta = reinterpret_cast<const float4*>(&tokE[(size_t)tk * EDIM + e8]);
  const float4* pa = reinterpret_cast<const float4*>(&posE[(size_t)tp * EDIM + e8]);
  float4 a0 = ta[0], a1 = ta[1], p0 = pa[0], p1 = pa[1];
  u16x8v o;
  o[0] = f2h_bits(a0.x + p0.x); o[1] = f2h_bits(a0.y + p0.y);
  o[2] = f2h_bits(a0.z + p0.z); o[3] = f2h_bits(a0.w + p0.w);
  o[4] = f2h_bits(a1.x + p1.x); o[5] = f2h_bits(a1.y + p1.y);
  o[6] = f2h_bits(a1.z + p1.z); o[7] = f2h_bits(a1.w + p1.w);
  *reinterpret_cast<u16x8v*>(&x[(size_t)row * EDIM + e8]) = o;
}

// ---------------- W{q,k,v}[h,e,d] (f32) -> Wt[n=mat*1024+h*64+d][e] (f16)
__global__ __launch_bounds__(256) void trans_qkvw(
    const float* __restrict__ Wq, const float* __restrict__ Wk,
    const float* __restrict__ Wv, unsigned short* __restrict__ Wt) {
  __shared__ float ts[64][65];
  int bid = blockIdx.x;          // 3*16*16 = 768
  int mat = bid >> 8;
  int h   = (bid >> 4) & 15;
  int et  = bid & 15;
  const float* src = (mat == 0 ? Wq : (mat == 1 ? Wk : Wv)) + (size_t)h * EDIM * DDIM;
  int t = threadIdx.x;
  int rr = t >> 4, c4 = (t & 15) * 4;
#pragma unroll
  for (int p = 0; p < 4; ++p) {
    int r = p * 16 + rr;  // e within tile
    float4 v = *reinterpret_cast<const float4*>(&src[(size_t)(et * 64 + r) * DDIM + c4]);
    ts[r][c4 + 0] = v.x; ts[r][c4 + 1] = v.y; ts[r][c4 + 2] = v.z; ts[r][c4 + 3] = v.w;
  }
  __syncthreads();
#pragma unroll
  for (int p = 0; p < 4; ++p) {
    int dr = p * 16 + rr;  // d
    u16x4v o;
#pragma unroll
    for (int j = 0; j < 4; ++j) o[j] = f2h_bits(ts[c4 + j][dr]);
    *reinterpret_cast<u16x4v*>(&Wt[((size_t)(mat * EDIM + h * 64 + dr)) * EDIM + et * 64 + c4]) = o;
  }
}

// ---------------- lm_W[e,v] (f32) -> lm_Wt[v,e] (f16)
__global__ __launch_bounds__(256) void trans_lmw(
    const float* __restrict__ W, unsigned short* __restrict__ Wt) {
  __shared__ float ts[64][65];
  int bid = blockIdx.x;        // 500 * 16 = 8000
  int vt = bid / 16, et = bid % 16;
  int t = threadIdx.x;
  int rr = t >> 4, c4 = (t & 15) * 4;
#pragma unroll
  for (int p = 0; p < 4; ++p) {
    int r = p * 16 + rr;  // e within tile
    float4 v = *reinterpret_cast<const float4*>(&W[(size_t)(et * 64 + r) * VOC + vt * 64 + c4]);
    ts[r][c4 + 0] = v.x; ts[r][c4 + 1] = v.y; ts[r][c4 + 2] = v.z; ts[r][c4 + 3] = v.w;
  }
  __syncthreads();
#pragma unroll
  for (int p = 0; p < 4; ++p) {
    int vr = p * 16 + rr;  // v within tile
    u16x4v o;
#pragma unroll
    for (int j = 0; j < 4; ++j) o[j] = f2h_bits(ts[c4 + j][vr]);
    *reinterpret_cast<u16x4v*>(&Wt[(size_t)(vt * 64 + vr) * EDIM + et * 64 + c4]) = o;
  }
}

// ---------------- 256x256 GEMM, depth-3 pipeline: A[M,K] f16, Bt[N,K] f16 -> C[M,N]
// 8 waves (2M x 4N). K is stepped in 32-col tiles. LDS = 4 slots x
// {A[256][32], B[256][32]} f16 = 4 x 32 KB = 128 KiB. At tile t we stage
// tile t+3 into slot (t+3)&3; the single per-tile barrier uses counted
// s_waitcnt vmcnt(8), draining exactly tile t+1's 4 loads while keeping
// tiles t+2,t+3 (8 loads) in flight (~6 phases ~1000 cyc > HBM latency).
// Slot (t+3)&3 == slot (t-1)&3 whose reads finished before this tile began.
// Bank-conflict swizzle: chunk c' = c ^ ((row>>1)&3) on 16B chunks, applied
// to BOTH the global_load_lds source and the ds_read address (involution).
template <bool F32OUT, bool BIAS>
__global__ __launch_bounds__(512, 2) void gemm256(
    const unsigned short* __restrict__ A, const unsigned short* __restrict__ Bt,
    float* __restrict__ Cf, unsigned short* __restrict__ Ch,
    const float* __restrict__ bias, int N, int K) {
  __shared__ __align__(16) unsigned short lds[65536];   // 128 KiB
  const int tid = threadIdx.x;
  const int w = tid >> 6, l = tid & 63;
  const int wr = w >> 2, wc = w & 3;      // 2 x 4 wave grid
  const int l15 = l & 15, lhi = l >> 4;

  // XCD-bijective block swizzle + M-fastest ordering (nby = 4096/256 = 16)
  const int nwg = gridDim.x;
  const int orig = blockIdx.x;
  const int swz = (orig & 7) * (nwg >> 3) + (orig >> 3);
  const int bx = swz >> 4;            // N-block
  const int by = swz & 15;            // M-block (fastest within XCD chunk)
  const int m0 = by * 256, n0 = bx * 256;

  // ds_read swizzled chunk (16B units within a 64B row of a [256][32] region)
  const int swzc = lhi ^ ((l15 >> 1) & 3);
  const int aOff = (wr * 128 + l15) * 32 + swzc * 8;          // A at slot+0
  const int bOff = 8192 + (wc * 64 + l15) * 32 + swzc * 8;    // B at slot+8192

  // staging lane -> (row, chunk); LDS chunk (l&3) holds global chunk
  // (l&3) ^ ((row>>1)&3) with row = l>>2
  const int sr = l >> 2;
  const int sc = (l & 3) ^ ((l >> 3) & 3);
  const unsigned short* PA = A  + (size_t)(m0 + w * 16 + sr) * K + sc * 8;
  const unsigned short* PB = Bt + (size_t)(n0 + w * 16 + sr) * K + sc * 8;
  const int dOff = w * 512;  // wave-uniform dest (16 rows * 32 els)

  // stage one matrix's [256][32] region for K-tile ts into slot
#define STAGE32(mat, Pm, ts, slot) do {                                       \
    gload_lds16(Pm + (size_t)(ts) * 32,                                       \
                &lds[(slot) * 16384 + (mat) * 8192 + dOff]);                  \
    gload_lds16(Pm + (size_t)128 * K + (size_t)(ts) * 32,                     \
                &lds[(slot) * 16384 + (mat) * 8192 + 4096 + dOff]);           \
  } while (0)

  f32x4 acc[8][4] = {};
  // prologue: stage tiles 0,1,2
  STAGE32(0, PA, 0, 0); STAGE32(1, PB, 0, 0);
  STAGE32(0, PA, 1, 1); STAGE32(1, PB, 1, 1);
  STAGE32(0, PA, 2, 2); STAGE32(1, PB, 2, 2);
  asm volatile("s_waitcnt vmcnt(8)" ::: "memory");   // tile 0 landed
  __builtin_amdgcn_sched_barrier(0);
  __builtin_amdgcn_s_barrier();

  const int NT = K >> 5;   // 32-col K-tiles
  for (int t = 0; t < NT; ++t) {
    const int base = (t & 3) * 16384;
    const int ts = (t + 3 < NT) ? (t + 3) : (NT - 1);  // clamp keeps vmcnt symmetric
    const int dslot = (t + 3) & 3;
    f16x8 af[4], bf[4];
    // ---------- phase 1: M rows half 0 ----------
    {
      const unsigned short* pa = &lds[base + aOff];
      const unsigned short* pb = &lds[base + bOff];
#pragma unroll
      for (int q = 0; q < 4; ++q) af[q] = *reinterpret_cast<const f16x8*>(pa + q * 512);
#pragma unroll
      for (int q = 0; q < 4; ++q) bf[q] = *reinterpret_cast<const f16x8*>(pb + q * 512);
      STAGE32(0, PA, ts, dslot);
      asm volatile("s_waitcnt lgkmcnt(0)" ::: "memory");
      __builtin_amdgcn_sched_barrier(0);
      __builtin_amdgcn_s_setprio(1);
#pragma unroll
      for (int mi = 0; mi < 4; ++mi)
#pragma unroll
        for (int ni = 0; ni < 4; ++ni)
          acc[mi][ni] = __builtin_amdgcn_mfma_f32_16x16x32_f16(af[mi], bf[ni], acc[mi][ni], 0, 0, 0);
      __builtin_amdgcn_s_setprio(0);
    }
    // ---------- phase 2: M rows half 1 (reuse bf) ----------
    {
      const unsigned short* pa = &lds[base + aOff + 2048];
#pragma unroll
      for (int q = 0; q < 4; ++q) af[q] = *reinterpret_cast<const f16x8*>(pa + q * 512);
      STAGE32(1, PB, ts, dslot);
      asm volatile("s_waitcnt lgkmcnt(0)" ::: "memory");
      __builtin_amdgcn_sched_barrier(0);
      __builtin_amdgcn_s_setprio(1);
#pragma unroll
      for (int mi = 0; mi < 4; ++mi)
#pragma unroll
        for (int ni = 0; ni < 4; ++ni)
          acc[4 + mi][ni] = __builtin_amdgcn_mfma_f32_16x16x32_f16(af[mi], bf[ni], acc[4 + mi][ni], 0, 0, 0);
      __builtin_amdgcn_s_setprio(0);
    }
    // single per-tile barrier: drain tile t+1's loads, keep t+2/t+3 in flight
    asm volatile("s_waitcnt vmcnt(8)" ::: "memory");
    __builtin_amdgcn_sched_barrier(0);
    __builtin_amdgcn_s_barrier();
  }
#undef STAGE32
  asm volatile("s_waitcnt vmcnt(0)" ::: "memory");  // drain tail loads

  // epilogue; C/D frag layout: col = lane&15, row = (lane>>4)*4 + r
#pragma unroll
  for (int ni = 0; ni < 4; ++ni) {
    const int col = n0 + wc * 64 + ni * 16 + l15;
    float bv = BIAS ? bias[col] : 0.0f;
#pragma unroll
    for (int mi = 0; mi < 8; ++mi) {
#pragma unroll
      for (int r = 0; r < 4; ++r) {
        const size_t row = (size_t)m0 + wr * 128 + mi * 16 + lhi * 4 + r;
        float v = acc[mi][ni][r] + bv;
        if constexpr (F32OUT) Cf[row * (size_t)N + col] = v;
        else                  Ch[row * (size_t)N + col] = f2h_bits(v);
      }
    }
  }
}

// ---------------- causal flash attention
// qkv[M, 3072]: cols [0,1024)=Q(h,d), [1024,2048)=K, [2048,3072)=V  (f16)
// one block = one (b,h,qtile of 64 rows); 4 waves x 16 q-rows; KV tiles of 64.
// Vt double-buffered; next V tile prefetched into regs at loop top (T14) and
// written to the other buffer after PV; ONE barrier per KV-tile.
__global__ __launch_bounds__(256) void attn_kernel(
    const unsigned short* __restrict__ qkv, unsigned short* __restrict__ out) {
  __shared__ unsigned short Vt[2][64 * 72];    // V^T tiles: [d][kv], padded
  __shared__ unsigned short Pl[4 * 16 * 72];   // per-wave P tile: [qrow][kv]
  const int bid = blockIdx.x;
  const int qt = bid & 31, bh = bid >> 5;
  const int b = bh >> 4, h = bh & 15;
  const int tid = threadIdx.x, w = tid >> 6, l = tid & 63;
  const int l15 = l & 15, lhi = l >> 4;
  const int q0 = qt * 64;
  const size_t RS = QKVN;  // row stride in elements
  const unsigned short* qbase = qkv + (size_t)b * TSEQ * RS + h * 64;
  const unsigned short* kbase = qbase + EDIM;
  const unsigned short* vbase = qbase + 2 * EDIM;

  // Q fragments stay in registers for the whole kernel
  f16x8 qa[2];
  {
    const int qrow = q0 + w * 16 + l15;
#pragma unroll
    for (int ks = 0; ks < 2; ++ks)
      qa[ks] = *reinterpret_cast<const f16x8*>(qbase + (size_t)qrow * RS + ks * 32 + lhi * 8);
  }
  // stage V tile 0 into Vt[0]
  const int vr_ = tid >> 3, vc8 = (tid & 7) * 8;
  {
#pragma unroll
    for (int p = 0; p < 2; ++p) {
      const int rr = vr_ + p * 32;
      u16x8v v = *reinterpret_cast<const u16x8v*>(vbase + (size_t)rr * RS + vc8);
#pragma unroll
      for (int j = 0; j < 8; ++j) Vt[0][(vc8 + j) * 72 + rr] = v[j];
    }
  }
  float m_run[4], l_run[4];
  f32x4 o[4] = {};
#pragma unroll
  for (int r = 0; r < 4; ++r) { m_run[r] = -__builtin_inff(); l_run[r] = 0.f; }
  const int myrow = q0 + w * 16 + lhi * 4;
  unsigned short* pl = &Pl[w * 16 * 72];
  __syncthreads();

  for (int kt = 0; kt <= qt; ++kt) {
    const int kv0 = kt * 64;
    // prefetch next V tile into regs (clamped; consumed after PV)
    const int tn = (kt + 1 <= qt) ? (kt + 1) : qt;
    u16x8v vpre[2];
#pragma unroll
    for (int p = 0; p < 2; ++p)
      vpre[p] = *reinterpret_cast<const u16x8v*>(
          vbase + (size_t)(tn * 64 + vr_ + p * 32) * RS + vc8);
    // S = Q K^T  (B-operand = K rows read straight from L2)
    f32x4 s[4];
    __builtin_amdgcn_s_setprio(1);
#pragma unroll
    for (int ct = 0; ct < 4; ++ct) {
      f32x4 acc = {};
#pragma unroll
      for (int ks = 0; ks < 2; ++ks) {
        f16x8 kb = *reinterpret_cast<const f16x8*>(
            kbase + (size_t)(kv0 + ct * 16 + l15) * RS + ks * 32 + lhi * 8);
        acc = __builtin_amdgcn_mfma_f32_16x16x32_f16(qa[ks], kb, acc, 0, 0, 0);
      }
      s[ct] = acc;
    }
    __builtin_amdgcn_s_setprio(0);
    // scale + causal mask
#pragma unroll
    for (int ct = 0; ct < 4; ++ct) {
      const int col = kv0 + ct * 16 + l15;
#pragma unroll
      for (int r = 0; r < 4; ++r) {
        float v = s[ct][r] * 0.125f;
        if (col > myrow + r) v = -__builtin_inff();
        s[ct][r] = v;
      }
    }
    // online softmax (rows live across a 16-lane group)
    float alpha[4];
#pragma unroll
    for (int r = 0; r < 4; ++r) {
      float mx = fmaxf(fmaxf(s[0][r], s[1][r]), fmaxf(s[2][r], s[3][r]));
      mx = fmaxf(mx, __shfl_xor(mx, 1)); mx = fmaxf(mx, __shfl_xor(mx, 2));
      mx = fmaxf(mx, __shfl_xor(mx, 4)); mx = fmaxf(mx, __shfl_xor(mx, 8));
      const float mn = fmaxf(m_run[r], mx);
      alpha[r] = __expf(m_run[r] - mn);   // exp(-inf)=0 on first tile
      m_run[r] = mn;
    }
    float rs[4] = {0.f, 0.f, 0.f, 0.f};
#pragma unroll
    for (int ct = 0; ct < 4; ++ct)
#pragma unroll
      for (int r = 0; r < 4; ++r) {
        const float p = __expf(s[ct][r] - m_run[r]);   // masked -> 0
        s[ct][r] = p;
        rs[r] += p;
      }
#pragma unroll
    for (int r = 0; r < 4; ++r) {
      float t = rs[r];
      t += __shfl_xor(t, 1); t += __shfl_xor(t, 2);
      t += __shfl_xor(t, 4); t += __shfl_xor(t, 8);
      l_run[r] = l_run[r] * alpha[r] + t;
    }
#pragma unroll
    for (int ct = 0; ct < 4; ++ct)
#pragma unroll
      for (int r = 0; r < 4; ++r) o[ct][r] *= alpha[r];
    // P (C-layout) -> LDS -> A-layout fragments
#pragma unroll
    for (int ct = 0; ct < 4; ++ct)
#pragma unroll
      for (int r = 0; r < 4; ++r)
        pl[(lhi * 4 + r) * 72 + ct * 16 + l15] = f2h_bits(s[ct][r]);
    // O += P V
    const unsigned short* vt = Vt[kt & 1];
#pragma unroll
    for (int ks = 0; ks < 2; ++ks) {
      f16x8 pa = *reinterpret_cast<const f16x8*>(&pl[l15 * 72 + ks * 32 + lhi * 8]);
      __builtin_amdgcn_s_setprio(1);
#pragma unroll
      for (int ct = 0; ct < 4; ++ct) {
        f16x8 vb = *reinterpret_cast<const f16x8*>(&vt[(ct * 16 + l15) * 72 + ks * 32 + lhi * 8]);
        o[ct] = __builtin_amdgcn_mfma_f32_16x16x32_f16(pa, vb, o[ct], 0, 0, 0);
      }
      __builtin_amdgcn_s_setprio(0);
    }
    // write prefetched V tile into the other buffer (uniform branch)
    if (kt < qt) {
      unsigned short* vtn = Vt[(kt + 1) & 1];
#pragma unroll
      for (int p = 0; p < 2; ++p) {
        const int rr = vr_ + p * 32;
#pragma unroll
        for (int j = 0; j < 8; ++j) vtn[(vc8 + j) * 72 + rr] = vpre[p][j];
      }
    }
    __syncthreads();
  }
  // epilogue: out[b*T + row, h*64 + d] = o / l
  unsigned short* obase = out + ((size_t)(b * TSEQ + q0 + w * 16)) * EDIM + h * 64;
#pragma unroll
  for (int ct = 0; ct < 4; ++ct)
#pragma unroll
    for (int r = 0; r < 4; ++r) {
      const float v = o[ct][r] / l_run[r];
      obase[(size_t)(lhi * 4 + r) * EDIM + ct * 16 + l15] = f2h_bits(v);
    }
}

extern "C" void kernel_launch(void* const* d_in, const int* in_sizes, int n_in,
                              void* d_out, int out_size, void* d_ws, size_t ws_size,
                              hipStream_t stream) {
  const int*   X    = (const int*)d_in[0];
  const float* tokE = (const float*)d_in[1];
  const float* posE = (const float*)d_in[2];
  const float* Wq   = (const float*)d_in[3];
  const float* Wk   = (const float*)d_in[4];
  const float* Wv   = (const float*)d_in[5];
  const float* lmW  = (const float*)d_in[6];
  const float* lmb  = (const float*)d_in[7];
  float* out = (float*)d_out;

  // workspace layout (f16 elements); total ~108.5 MB
  unsigned short* ws   = (unsigned short*)d_ws;
  unsigned short* x    = ws;                              // [4096,1024]
  unsigned short* att  = x    + (size_t)MROWS * EDIM;     // [4096,1024]
  unsigned short* wqkv = att  + (size_t)MROWS * EDIM;     // [3072,1024]
  unsigned short* qkv  = wqkv + (size_t)QKVN * EDIM;      // [4096,3072]
  unsigned short* lmWt = qkv  + (size_t)MROWS * QKVN;     // [32000,1024]

  embed_kernel<<<(MROWS * EDIM / 8) / 256, 256, 0, stream>>>(X, tokE, posE, x);
  trans_qkvw<<<3 * NH * (EDIM / 64), 256, 0, stream>>>(Wq, Wk, Wv, wqkv);
  trans_lmw<<<(VOC / 64) * (EDIM / 64), 256, 0, stream>>>(lmW, lmWt);
  // QKV proj: M=4096, N=3072, K=1024 -> 12*16 = 192 blocks (%8==0)
  gemm256<false, false><<<(QKVN / 256) * (MROWS / 256), 512, 0, stream>>>(
      x, wqkv, nullptr, qkv, nullptr, QKVN, EDIM);
  attn_kernel<<<NB * NH * (TSEQ / 64), 256, 0, stream>>>(qkv, att);
  // LM head: M=4096, N=32000, K=1024 -> 125*16 = 2000 blocks (%8==0)
  gemm256<true, true><<<(VOC / 256) * (MROWS / 256), 512, 0, stream>>>(
      att, lmWt, out, nullptr, lmb, VOC, EDIM);
}

// Round 4
// 589.526 us; speedup vs baseline: 1.2059x; 1.1127x over previous
//
#include <hip/hip_runtime.h>
#include <hip/hip_bf16.h>
#include <cstdint>

// Problem dims
#define TSEQ 2048
#define NB   2
#define NH   16
#define EDIM 1024
#define DDIM 64
#define VOC  32000
#define MROWS (NB*TSEQ)   // 4096
#define QKVN  (3*EDIM)    // 3072

typedef _Float16 f16x8 __attribute__((ext_vector_type(8)));
typedef float    f32x4 __attribute__((ext_vector_type(4)));
typedef unsigned short u16x4v __attribute__((ext_vector_type(4)));
typedef unsigned short u16x8v __attribute__((ext_vector_type(8)));

__device__ __forceinline__ unsigned short f2h_bits(float v) {
  return __builtin_bit_cast(unsigned short, (_Float16)v);
}

// async global->LDS, 16B per lane. LDS dest is wave-uniform base; lane i
// writes bytes [16*i, 16*i+16). Per-lane global source address is free.
__device__ __forceinline__ void gload_lds16(const void* g, void* l) {
  __builtin_amdgcn_global_load_lds((__attribute__((address_space(1))) void*)(g),
                                   (__attribute__((address_space(3))) void*)(l),
                                   16, 0, 0);
}

// ---------------- embedding: x[row,e] = tok_emb[X[row],e] + pos_emb[row%T,e] (f16 out)
__global__ __launch_bounds__(256) void embed_kernel(
    const int* __restrict__ X, const float* __restrict__ tokE,
    const float* __restrict__ posE, unsigned short* __restrict__ x) {
  int g = blockIdx.x * 256 + threadIdx.x;
  int row = g >> 7;            // 128 threads per row of 1024
  int e8  = (g & 127) * 8;
  int tk  = X[row];
  int tp  = row & (TSEQ - 1);
  const float4* ta = reinterpret_cast<const float4*>(&tokE[(size_t)tk * EDIM + e8]);
  const float4* pa = reinterpret_cast<const float4*>(&posE[(size_t)tp * EDIM + e8]);
  float4 a0 = ta[0], a1 = ta[1], p0 = pa[0], p1 = pa[1];
  u16x8v o;
  o[0] = f2h_bits(a0.x + p0.x); o[1] = f2h_bits(a0.y + p0.y);
  o[2] = f2h_bits(a0.z + p0.z); o[3] = f2h_bits(a0.w + p0.w);
  o[4] = f2h_bits(a1.x + p1.x); o[5] = f2h_bits(a1.y + p1.y);
  o[6] = f2h_bits(a1.z + p1.z); o[7] = f2h_bits(a1.w + p1.w);
  *reinterpret_cast<u16x8v*>(&x[(size_t)row * EDIM + e8]) = o;
}

// ---------------- W{q,k,v}[h,e,d] (f32) -> Wt[n=mat*1024+h*64+d][e] (f16)
__global__ __launch_bounds__(256) void trans_qkvw(
    const float* __restrict__ Wq, const float* __restrict__ Wk,
    const float* __restrict__ Wv, unsigned short* __restrict__ Wt) {
  __shared__ float ts[64][65];
  int bid = blockIdx.x;          // 3*16*16 = 768
  int mat = bid >> 8;
  int h   = (bid >> 4) & 15;
  int et  = bid & 15;
  const float* src = (mat == 0 ? Wq : (mat == 1 ? Wk : Wv)) + (size_t)h * EDIM * DDIM;
  int t = threadIdx.x;
  int rr = t >> 4, c4 = (t & 15) * 4;
#pragma unroll
  for (int p = 0; p < 4; ++p) {
    int r = p * 16 + rr;  // e within tile
    float4 v = *reinterpret_cast<const float4*>(&src[(size_t)(et * 64 + r) * DDIM + c4]);
    ts[r][c4 + 0] = v.x; ts[r][c4 + 1] = v.y; ts[r][c4 + 2] = v.z; ts[r][c4 + 3] = v.w;
  }
  __syncthreads();
#pragma unroll
  for (int p = 0; p < 4; ++p) {
    int dr = p * 16 + rr;  // d
    u16x4v o;
#pragma unroll
    for (int j = 0; j < 4; ++j) o[j] = f2h_bits(ts[c4 + j][dr]);
    *reinterpret_cast<u16x4v*>(&Wt[((size_t)(mat * EDIM + h * 64 + dr)) * EDIM + et * 64 + c4]) = o;
  }
}

// ---------------- lm_W[e,v] (f32) -> lm_Wt[v,e] (f16)
__global__ __launch_bounds__(256) void trans_lmw(
    const float* __restrict__ W, unsigned short* __restrict__ Wt) {
  __shared__ float ts[64][65];
  int bid = blockIdx.x;        // 500 * 16 = 8000
  int vt = bid / 16, et = bid % 16;
  int t = threadIdx.x;
  int rr = t >> 4, c4 = (t & 15) * 4;
#pragma unroll
  for (int p = 0; p < 4; ++p) {
    int r = p * 16 + rr;  // e within tile
    float4 v = *reinterpret_cast<const float4*>(&W[(size_t)(et * 64 + r) * VOC + vt * 64 + c4]);
    ts[r][c4 + 0] = v.x; ts[r][c4 + 1] = v.y; ts[r][c4 + 2] = v.z; ts[r][c4 + 3] = v.w;
  }
  __syncthreads();
#pragma unroll
  for (int p = 0; p < 4; ++p) {
    int vr = p * 16 + rr;  // v within tile
    u16x4v o;
#pragma unroll
    for (int j = 0; j < 4; ++j) o[j] = f2h_bits(ts[c4 + j][vr]);
    *reinterpret_cast<u16x4v*>(&Wt[(size_t)(vt * 64 + vr) * EDIM + et * 64 + c4]) = o;
  }
}

// ---------------- 128x256 GEMM (A[M,K] f16, Bt[N,K] f16 -> C[M,N])
// 8 waves (2M x 4N), wave tile 64x64 (acc 64 regs -> 4 waves/SIMD), BK=32.
// LDS: 3 slots x {A[128][32], B[256][32]} = 3 x 24 KB = 72 KB -> 2 blocks/CU.
// Depth-2 counted pipeline: at tile t issue stage(t+2) into slot (t+2)%3;
// end-of-tile barrier uses vmcnt(3): drains stage(t+1)'s 3 loads, keeps
// stage(t+2) in flight (~2 tile-periods > HBM latency with TLP on top).
// Bank-conflict swizzle (verified, conflicts=0): 16B chunk c stored at
// c ^ ((row>>1)&3), applied to BOTH global_load_lds source and ds_read addr.
// F32OUT uses non-temporal stores (C never re-read; avoids write-allocate).
template <bool F32OUT, bool BIAS>
__global__ __launch_bounds__(512, 4) void gemm128(
    const unsigned short* __restrict__ A, const unsigned short* __restrict__ Bt,
    float* __restrict__ Cf, unsigned short* __restrict__ Ch,
    const float* __restrict__ bias, int N, int K) {
  __shared__ __align__(16) unsigned short lds[3 * 12288];   // 72 KiB
  const int tid = threadIdx.x;
  const int w = tid >> 6, l = tid & 63;
  const int wr = w >> 2, wc = w & 3;      // 2 x 4 wave grid
  const int l15 = l & 15, lhi = l >> 4;

  // XCD-bijective block swizzle; M-fastest (nby = 4096/128 = 32)
  const int nwg = gridDim.x;
  const int orig = blockIdx.x;
  const int swz = (orig & 7) * (nwg >> 3) + (orig >> 3);
  const int bx = swz >> 5;            // N-block
  const int by = swz & 31;            // M-block (fastest within XCD chunk)
  const int m0 = by * 128, n0 = bx * 256;

  // ds_read swizzled chunk (16B units within a 64B row of a [.][32] region)
  const int swzc = lhi ^ ((l15 >> 1) & 3);
  const int aOff = (wr * 64 + l15) * 32 + swzc * 8;           // A region at +0
  const int bOff = 4096 + (wc * 64 + l15) * 32 + swzc * 8;    // B region at +4096

  // staging lane -> (row, chunk); LDS chunk (l&3) holds global chunk
  // (l&3) ^ ((row>>1)&3) with row = l>>2
  const int sr = l >> 2;
  const int sc = (l & 3) ^ ((l >> 3) & 3);
  const unsigned short* PA = A  + (size_t)(m0 + w * 16 + sr) * K + sc * 8;
  const unsigned short* PB = Bt + (size_t)(n0 + w * 16 + sr) * K + sc * 8;
  const int dOff = w * 512;  // wave-uniform dest (16 rows * 32 els)

  // stage K-tile ts into slot (3 loads/wave: A rows 0-127, B rows 0-127,128-255)
#define STAGE32(ts, slot) do {                                                \
    gload_lds16(PA + (size_t)(ts) * 32, &lds[(slot) * 12288 + dOff]);         \
    gload_lds16(PB + (size_t)(ts) * 32, &lds[(slot) * 12288 + 4096 + dOff]);  \
    gload_lds16(PB + (size_t)128 * K + (size_t)(ts) * 32,                     \
                &lds[(slot) * 12288 + 8192 + dOff]);                          \
  } while (0)

  f32x4 acc[4][4] = {};
  // prologue: stage tiles 0,1
  STAGE32(0, 0);
  STAGE32(1, 1);
  asm volatile("s_waitcnt vmcnt(3)" ::: "memory");   // tile 0 landed
  __builtin_amdgcn_sched_barrier(0);
  __builtin_amdgcn_s_barrier();

  const int NT = K >> 5;   // 32-col K-tiles
  int slotC = 0;           // t % 3
  for (int t = 0; t < NT; ++t) {
    const int base = slotC * 12288;
    const int ts = (t + 2 < NT) ? (t + 2) : (NT - 1);  // clamp keeps vmcnt symmetric
    int dslot = slotC + 2; if (dslot >= 3) dslot -= 3; // (t+2)%3
    STAGE32(ts, dslot);
    f16x8 af[4], bf[4];
#pragma unroll
    for (int q = 0; q < 4; ++q) af[q] = *reinterpret_cast<const f16x8*>(&lds[base + aOff + q * 512]);
#pragma unroll
    for (int q = 0; q < 4; ++q) bf[q] = *reinterpret_cast<const f16x8*>(&lds[base + bOff + q * 512]);
    asm volatile("s_waitcnt lgkmcnt(0)" ::: "memory");
    __builtin_amdgcn_sched_barrier(0);
    __builtin_amdgcn_s_setprio(1);
#pragma unroll
    for (int mi = 0; mi < 4; ++mi)
#pragma unroll
      for (int ni = 0; ni < 4; ++ni)
        acc[mi][ni] = __builtin_amdgcn_mfma_f32_16x16x32_f16(af[mi], bf[ni], acc[mi][ni], 0, 0, 0);
    __builtin_amdgcn_s_setprio(0);
    // drain stage(t+1) (3 oldest), keep stage(t+2) (3 newest) in flight
    asm volatile("s_waitcnt vmcnt(3)" ::: "memory");
    __builtin_amdgcn_sched_barrier(0);
    __builtin_amdgcn_s_barrier();
    ++slotC; if (slotC == 3) slotC = 0;
  }
#undef STAGE32
  asm volatile("s_waitcnt vmcnt(0)" ::: "memory");  // drain tail loads

  // epilogue; C/D frag layout: col = lane&15, row = (lane>>4)*4 + r
#pragma unroll
  for (int ni = 0; ni < 4; ++ni) {
    const int col = n0 + wc * 64 + ni * 16 + l15;
    float bv = BIAS ? bias[col] : 0.0f;
#pragma unroll
    for (int mi = 0; mi < 4; ++mi) {
#pragma unroll
      for (int r = 0; r < 4; ++r) {
        const size_t row = (size_t)m0 + wr * 64 + mi * 16 + lhi * 4 + r;
        float v = acc[mi][ni][r] + bv;
        if constexpr (F32OUT) __builtin_nontemporal_store(v, &Cf[row * (size_t)N + col]);
        else                  Ch[row * (size_t)N + col] = f2h_bits(v);
      }
    }
  }
}

// ---------------- causal flash attention
// qkv[M, 3072]: cols [0,1024)=Q(h,d), [1024,2048)=K, [2048,3072)=V  (f16)
// one block = one (b,h,qtile of 64 rows); 4 waves x 16 q-rows; KV tiles of 64.
// Vt double-buffered; next V tile prefetched into regs at loop top (T14) and
// written to the other buffer after PV; ONE barrier per KV-tile.
__global__ __launch_bounds__(256) void attn_kernel(
    const unsigned short* __restrict__ qkv, unsigned short* __restrict__ out) {
  __shared__ unsigned short Vt[2][64 * 72];    // V^T tiles: [d][kv], padded
  __shared__ unsigned short Pl[4 * 16 * 72];   // per-wave P tile: [qrow][kv]
  const int bid = blockIdx.x;
  const int qt = bid & 31, bh = bid >> 5;
  const int b = bh >> 4, h = bh & 15;
  const int tid = threadIdx.x, w = tid >> 6, l = tid & 63;
  const int l15 = l & 15, lhi = l >> 4;
  const int q0 = qt * 64;
  const size_t RS = QKVN;  // row stride in elements
  const unsigned short* qbase = qkv + (size_t)b * TSEQ * RS + h * 64;
  const unsigned short* kbase = qbase + EDIM;
  const unsigned short* vbase = qbase + 2 * EDIM;

  // Q fragments stay in registers for the whole kernel
  f16x8 qa[2];
  {
    const int qrow = q0 + w * 16 + l15;
#pragma unroll
    for (int ks = 0; ks < 2; ++ks)
      qa[ks] = *reinterpret_cast<const f16x8*>(qbase + (size_t)qrow * RS + ks * 32 + lhi * 8);
  }
  // stage V tile 0 into Vt[0]
  const int vr_ = tid >> 3, vc8 = (tid & 7) * 8;
  {
#pragma unroll
    for (int p = 0; p < 2; ++p) {
      const int rr = vr_ + p * 32;
      u16x8v v = *reinterpret_cast<const u16x8v*>(vbase + (size_t)rr * RS + vc8);
#pragma unroll
      for (int j = 0; j < 8; ++j) Vt[0][(vc8 + j) * 72 + rr] = v[j];
    }
  }
  float m_run[4], l_run[4];
  f32x4 o[4] = {};
#pragma unroll
  for (int r = 0; r < 4; ++r) { m_run[r] = -__builtin_inff(); l_run[r] = 0.f; }
  const int myrow = q0 + w * 16 + lhi * 4;
  unsigned short* pl = &Pl[w * 16 * 72];
  __syncthreads();

  for (int kt = 0; kt <= qt; ++kt) {
    const int kv0 = kt * 64;
    // prefetch next V tile into regs (clamped; consumed after PV)
    const int tn = (kt + 1 <= qt) ? (kt + 1) : qt;
    u16x8v vpre[2];
#pragma unroll
    for (int p = 0; p < 2; ++p)
      vpre[p] = *reinterpret_cast<const u16x8v*>(
          vbase + (size_t)(tn * 64 + vr_ + p * 32) * RS + vc8);
    // S = Q K^T  (B-operand = K rows read straight from L2)
    f32x4 s[4];
    __builtin_amdgcn_s_setprio(1);
#pragma unroll
    for (int ct = 0; ct < 4; ++ct) {
      f32x4 acc = {};
#pragma unroll
      for (int ks = 0; ks < 2; ++ks) {
        f16x8 kb = *reinterpret_cast<const f16x8*>(
            kbase + (size_t)(kv0 + ct * 16 + l15) * RS + ks * 32 + lhi * 8);
        acc = __builtin_amdgcn_mfma_f32_16x16x32_f16(qa[ks], kb, acc, 0, 0, 0);
      }
      s[ct] = acc;
    }
    __builtin_amdgcn_s_setprio(0);
    // scale + causal mask
#pragma unroll
    for (int ct = 0; ct < 4; ++ct) {
      const int col = kv0 + ct * 16 + l15;
#pragma unroll
      for (int r = 0; r < 4; ++r) {
        float v = s[ct][r] * 0.125f;
        if (col > myrow + r) v = -__builtin_inff();
        s[ct][r] = v;
      }
    }
    // online softmax (rows live across a 16-lane group)
    float alpha[4];
#pragma unroll
    for (int r = 0; r < 4; ++r) {
      float mx = fmaxf(fmaxf(s[0][r], s[1][r]), fmaxf(s[2][r], s[3][r]));
      mx = fmaxf(mx, __shfl_xor(mx, 1)); mx = fmaxf(mx, __shfl_xor(mx, 2));
      mx = fmaxf(mx, __shfl_xor(mx, 4)); mx = fmaxf(mx, __shfl_xor(mx, 8));
      const float mn = fmaxf(m_run[r], mx);
      alpha[r] = __expf(m_run[r] - mn);   // exp(-inf)=0 on first tile
      m_run[r] = mn;
    }
    float rs[4] = {0.f, 0.f, 0.f, 0.f};
#pragma unroll
    for (int ct = 0; ct < 4; ++ct)
#pragma unroll
      for (int r = 0; r < 4; ++r) {
        const float p = __expf(s[ct][r] - m_run[r]);   // masked -> 0
        s[ct][r] = p;
        rs[r] += p;
      }
#pragma unroll
    for (int r = 0; r < 4; ++r) {
      float t = rs[r];
      t += __shfl_xor(t, 1); t += __shfl_xor(t, 2);
      t += __shfl_xor(t, 4); t += __shfl_xor(t, 8);
      l_run[r] = l_run[r] * alpha[r] + t;
    }
#pragma unroll
    for (int ct = 0; ct < 4; ++ct)
#pragma unroll
      for (int r = 0; r < 4; ++r) o[ct][r] *= alpha[r];
    // P (C-layout) -> LDS -> A-layout fragments
#pragma unroll
    for (int ct = 0; ct < 4; ++ct)
#pragma unroll
      for (int r = 0; r < 4; ++r)
        pl[(lhi * 4 + r) * 72 + ct * 16 + l15] = f2h_bits(s[ct][r]);
    // O += P V
    const unsigned short* vt = Vt[kt & 1];
#pragma unroll
    for (int ks = 0; ks < 2; ++ks) {
      f16x8 pa = *reinterpret_cast<const f16x8*>(&pl[l15 * 72 + ks * 32 + lhi * 8]);
      __builtin_amdgcn_s_setprio(1);
#pragma unroll
      for (int ct = 0; ct < 4; ++ct) {
        f16x8 vb = *reinterpret_cast<const f16x8*>(&vt[(ct * 16 + l15) * 72 + ks * 32 + lhi * 8]);
        o[ct] = __builtin_amdgcn_mfma_f32_16x16x32_f16(pa, vb, o[ct], 0, 0, 0);
      }
      __builtin_amdgcn_s_setprio(0);
    }
    // write prefetched V tile into the other buffer (uniform branch)
    if (kt < qt) {
      unsigned short* vtn = Vt[(kt + 1) & 1];
#pragma unroll
      for (int p = 0; p < 2; ++p) {
        const int rr = vr_ + p * 32;
#pragma unroll
        for (int j = 0; j < 8; ++j) vtn[(vc8 + j) * 72 + rr] = vpre[p][j];
      }
    }
    __syncthreads();
  }
  // epilogue: out[b*T + row, h*64 + d] = o / l  (rcp once per row)
  unsigned short* obase = out + ((size_t)(b * TSEQ + q0 + w * 16)) * EDIM + h * 64;
#pragma unroll
  for (int r = 0; r < 4; ++r) {
    const float linv = 1.0f / l_run[r];
#pragma unroll
    for (int ct = 0; ct < 4; ++ct) {
      obase[(size_t)(lhi * 4 + r) * EDIM + ct * 16 + l15] = f2h_bits(o[ct][r] * linv);
    }
  }
}

extern "C" void kernel_launch(void* const* d_in, const int* in_sizes, int n_in,
                              void* d_out, int out_size, void* d_ws, size_t ws_size,
                              hipStream_t stream) {
  const int*   X    = (const int*)d_in[0];
  const float* tokE = (const float*)d_in[1];
  const float* posE = (const float*)d_in[2];
  const float* Wq   = (const float*)d_in[3];
  const float* Wk   = (const float*)d_in[4];
  const float* Wv   = (const float*)d_in[5];
  const float* lmW  = (const float*)d_in[6];
  const float* lmb  = (const float*)d_in[7];
  float* out = (float*)d_out;

  // workspace layout (f16 elements); total ~108.5 MB
  unsigned short* ws   = (unsigned short*)d_ws;
  unsigned short* x    = ws;                              // [4096,1024]
  unsigned short* att  = x    + (size_t)MROWS * EDIM;     // [4096,1024]
  unsigned short* wqkv = att  + (size_t)MROWS * EDIM;     // [3072,1024]
  unsigned short* qkv  = wqkv + (size_t)QKVN * EDIM;      // [4096,3072]
  unsigned short* lmWt = qkv  + (size_t)MROWS * QKVN;     // [32000,1024]

  embed_kernel<<<(MROWS * EDIM / 8) / 256, 256, 0, stream>>>(X, tokE, posE, x);
  trans_qkvw<<<3 * NH * (EDIM / 64), 256, 0, stream>>>(Wq, Wk, Wv, wqkv);
  trans_lmw<<<(VOC / 64) * (EDIM / 64), 256, 0, stream>>>(lmW, lmWt);
  // QKV proj: M=4096, N=3072, K=1024 -> (3072/256)*(4096/128) = 12*32 = 384 blocks
  gemm128<false, false><<<(QKVN / 256) * (MROWS / 128), 512, 0, stream>>>(
      x, wqkv, nullptr, qkv, nullptr, QKVN, EDIM);
  attn_kernel<<<NB * NH * (TSEQ / 64), 256, 0, stream>>>(qkv, att);
  // LM head: M=4096, N=32000, K=1024 -> (32000/256)*(4096/128) = 125*32 = 4000 blocks
  gemm128<true, true><<<(VOC / 256) * (MROWS / 128), 512, 0, stream>>>(
      att, lmWt, out, nullptr, lmb, VOC, EDIM);
}

// Round 5
// 559.591 us; speedup vs baseline: 1.2704x; 1.0535x over previous
//
#include <hip/hip_runtime.h>
#include <hip/hip_bf16.h>
#include <cstdint>

// Problem dims
#define TSEQ 2048
#define NB   2
#define NH   16
#define EDIM 1024
#define DDIM 64
#define VOC  32000
#define MROWS (NB*TSEQ)   // 4096
#define QKVN  (3*EDIM)    // 3072

typedef _Float16 f16x8 __attribute__((ext_vector_type(8)));
typedef float    f32x4 __attribute__((ext_vector_type(4)));
typedef unsigned short u16x4v __attribute__((ext_vector_type(4)));
typedef unsigned short u16x8v __attribute__((ext_vector_type(8)));

__device__ __forceinline__ unsigned short f2h_bits(float v) {
  return __builtin_bit_cast(unsigned short, (_Float16)v);
}

// async global->LDS, 16B per lane. LDS dest is wave-uniform base; lane i
// writes bytes [16*i, 16*i+16). Per-lane global source address is free.
__device__ __forceinline__ void gload_lds16(const void* g, void* l) {
  __builtin_amdgcn_global_load_lds((__attribute__((address_space(1))) void*)(g),
                                   (__attribute__((address_space(3))) void*)(l),
                                   16, 0, 0);
}

// ---------------- embedding: x[row,e] = tok_emb[X[row],e] + pos_emb[row%T,e] (f16 out)
__global__ __launch_bounds__(256) void embed_kernel(
    const int* __restrict__ X, const float* __restrict__ tokE,
    const float* __restrict__ posE, unsigned short* __restrict__ x) {
  int g = blockIdx.x * 256 + threadIdx.x;
  int row = g >> 7;            // 128 threads per row of 1024
  int e8  = (g & 127) * 8;
  int tk  = X[row];
  int tp  = row & (TSEQ - 1);
  const float4* ta = reinterpret_cast<const float4*>(&tokE[(size_t)tk * EDIM + e8]);
  const float4* pa = reinterpret_cast<const float4*>(&posE[(size_t)tp * EDIM + e8]);
  float4 a0 = ta[0], a1 = ta[1], p0 = pa[0], p1 = pa[1];
  u16x8v o;
  o[0] = f2h_bits(a0.x + p0.x); o[1] = f2h_bits(a0.y + p0.y);
  o[2] = f2h_bits(a0.z + p0.z); o[3] = f2h_bits(a0.w + p0.w);
  o[4] = f2h_bits(a1.x + p1.x); o[5] = f2h_bits(a1.y + p1.y);
  o[6] = f2h_bits(a1.z + p1.z); o[7] = f2h_bits(a1.w + p1.w);
  *reinterpret_cast<u16x8v*>(&x[(size_t)row * EDIM + e8]) = o;
}

// ---------------- W{q,k,v}[h,e,d] (f32) -> Wt[n=mat*1024+h*64+d][e] (f16)
__global__ __launch_bounds__(256) void trans_qkvw(
    const float* __restrict__ Wq, const float* __restrict__ Wk,
    const float* __restrict__ Wv, unsigned short* __restrict__ Wt) {
  __shared__ float ts[64][65];
  int bid = blockIdx.x;          // 3*16*16 = 768
  int mat = bid >> 8;
  int h   = (bid >> 4) & 15;
  int et  = bid & 15;
  const float* src = (mat == 0 ? Wq : (mat == 1 ? Wk : Wv)) + (size_t)h * EDIM * DDIM;
  int t = threadIdx.x;
  int rr = t >> 4, c4 = (t & 15) * 4;
#pragma unroll
  for (int p = 0; p < 4; ++p) {
    int r = p * 16 + rr;  // e within tile
    float4 v = *reinterpret_cast<const float4*>(&src[(size_t)(et * 64 + r) * DDIM + c4]);
    ts[r][c4 + 0] = v.x; ts[r][c4 + 1] = v.y; ts[r][c4 + 2] = v.z; ts[r][c4 + 3] = v.w;
  }
  __syncthreads();
#pragma unroll
  for (int p = 0; p < 4; ++p) {
    int dr = p * 16 + rr;  // d
    u16x4v o;
#pragma unroll
    for (int j = 0; j < 4; ++j) o[j] = f2h_bits(ts[c4 + j][dr]);
    *reinterpret_cast<u16x4v*>(&Wt[((size_t)(mat * EDIM + h * 64 + dr)) * EDIM + et * 64 + c4]) = o;
  }
}

// ---------------- lm_W[e,v] (f32) -> lm_Wt[v,e] (f16)
__global__ __launch_bounds__(256) void trans_lmw(
    const float* __restrict__ W, unsigned short* __restrict__ Wt) {
  __shared__ float ts[64][65];
  int bid = blockIdx.x;        // 500 * 16 = 8000
  int vt = bid / 16, et = bid % 16;
  int t = threadIdx.x;
  int rr = t >> 4, c4 = (t & 15) * 4;
#pragma unroll
  for (int p = 0; p < 4; ++p) {
    int r = p * 16 + rr;  // e within tile
    float4 v = *reinterpret_cast<const float4*>(&W[(size_t)(et * 64 + r) * VOC + vt * 64 + c4]);
    ts[r][c4 + 0] = v.x; ts[r][c4 + 1] = v.y; ts[r][c4 + 2] = v.z; ts[r][c4 + 3] = v.w;
  }
  __syncthreads();
#pragma unroll
  for (int p = 0; p < 4; ++p) {
    int vr = p * 16 + rr;  // v within tile
    u16x4v o;
#pragma unroll
    for (int j = 0; j < 4; ++j) o[j] = f2h_bits(ts[c4 + j][vr]);
    *reinterpret_cast<u16x4v*>(&Wt[(size_t)(vt * 64 + vr) * EDIM + et * 64 + c4]) = o;
  }
}

// ---------------- 128x256 GEMM (A[M,K] f16, Bt[N,K] f16 -> C[M,N])
// 8 waves (2M x 4N), wave tile 64x64, BK=32, 3-slot LDS (72 KB, 2 blocks/CU),
// depth-2 counted pipeline (vmcnt(3) per-tile barrier), chunk-XOR swizzle
// (conflicts measured 0). Block order: PLAIN M-fastest linear (NO XCD
// swizzle): all XCDs walk the same B-panel together so B is fetched from
// HBM ~once and A stays L3-resident despite the C-write stream thrash.
// (R4 post-mortem: XCD-chunked order re-fetched B per XCD -> 558 MB fetch.)
template <bool F32OUT, bool BIAS>
__global__ __launch_bounds__(512, 4) void gemm128(
    const unsigned short* __restrict__ A, const unsigned short* __restrict__ Bt,
    float* __restrict__ Cf, unsigned short* __restrict__ Ch,
    const float* __restrict__ bias, int N, int K) {
  __shared__ __align__(16) unsigned short lds[3 * 12288];   // 72 KiB
  const int tid = threadIdx.x;
  const int w = tid >> 6, l = tid & 63;
  const int wr = w >> 2, wc = w & 3;      // 2 x 4 wave grid
  const int l15 = l & 15, lhi = l >> 4;

  // plain linear order, M-fastest (nby = 4096/128 = 32)
  const int orig = blockIdx.x;
  const int bx = orig >> 5;           // N-block
  const int by = orig & 31;           // M-block (fastest)
  const int m0 = by * 128, n0 = bx * 256;

  // ds_read swizzled chunk (16B units within a 64B row of a [.][32] region)
  const int swzc = lhi ^ ((l15 >> 1) & 3);
  const int aOff = (wr * 64 + l15) * 32 + swzc * 8;           // A region at +0
  const int bOff = 4096 + (wc * 64 + l15) * 32 + swzc * 8;    // B region at +4096

  // staging lane -> (row, chunk); LDS chunk (l&3) holds global chunk
  // (l&3) ^ ((row>>1)&3) with row = l>>2
  const int sr = l >> 2;
  const int sc = (l & 3) ^ ((l >> 3) & 3);
  const unsigned short* PA = A  + (size_t)(m0 + w * 16 + sr) * K + sc * 8;
  const unsigned short* PB = Bt + (size_t)(n0 + w * 16 + sr) * K + sc * 8;
  const int dOff = w * 512;  // wave-uniform dest (16 rows * 32 els)

  // stage K-tile ts into slot (3 loads/wave: A rows 0-127, B rows 0-127,128-255)
#define STAGE32(ts, slot) do {                                                \
    gload_lds16(PA + (size_t)(ts) * 32, &lds[(slot) * 12288 + dOff]);         \
    gload_lds16(PB + (size_t)(ts) * 32, &lds[(slot) * 12288 + 4096 + dOff]);  \
    gload_lds16(PB + (size_t)128 * K + (size_t)(ts) * 32,                     \
                &lds[(slot) * 12288 + 8192 + dOff]);                          \
  } while (0)

  f32x4 acc[4][4] = {};
  // prologue: stage tiles 0,1
  STAGE32(0, 0);
  STAGE32(1, 1);
  asm volatile("s_waitcnt vmcnt(3)" ::: "memory");   // tile 0 landed
  __builtin_amdgcn_sched_barrier(0);
  __builtin_amdgcn_s_barrier();

  const int NT = K >> 5;   // 32-col K-tiles
  int slotC = 0;           // t % 3
  for (int t = 0; t < NT; ++t) {
    const int base = slotC * 12288;
    const int ts = (t + 2 < NT) ? (t + 2) : (NT - 1);  // clamp keeps vmcnt symmetric
    int dslot = slotC + 2; if (dslot >= 3) dslot -= 3; // (t+2)%3
    STAGE32(ts, dslot);
    f16x8 af[4], bf[4];
#pragma unroll
    for (int q = 0; q < 4; ++q) af[q] = *reinterpret_cast<const f16x8*>(&lds[base + aOff + q * 512]);
#pragma unroll
    for (int q = 0; q < 4; ++q) bf[q] = *reinterpret_cast<const f16x8*>(&lds[base + bOff + q * 512]);
    asm volatile("s_waitcnt lgkmcnt(0)" ::: "memory");
    __builtin_amdgcn_sched_barrier(0);
    __builtin_amdgcn_s_setprio(1);
#pragma unroll
    for (int mi = 0; mi < 4; ++mi)
#pragma unroll
      for (int ni = 0; ni < 4; ++ni)
        acc[mi][ni] = __builtin_amdgcn_mfma_f32_16x16x32_f16(af[mi], bf[ni], acc[mi][ni], 0, 0, 0);
    __builtin_amdgcn_s_setprio(0);
    // drain stage(t+1) (3 oldest), keep stage(t+2) (3 newest) in flight
    asm volatile("s_waitcnt vmcnt(3)" ::: "memory");
    __builtin_amdgcn_sched_barrier(0);
    __builtin_amdgcn_s_barrier();
    ++slotC; if (slotC == 3) slotC = 0;
  }
#undef STAGE32
  asm volatile("s_waitcnt vmcnt(0)" ::: "memory");  // drain tail loads

  // epilogue; C/D frag layout: col = lane&15, row = (lane>>4)*4 + r
#pragma unroll
  for (int ni = 0; ni < 4; ++ni) {
    const int col = n0 + wc * 64 + ni * 16 + l15;
    float bv = BIAS ? bias[col] : 0.0f;
#pragma unroll
    for (int mi = 0; mi < 4; ++mi) {
#pragma unroll
      for (int r = 0; r < 4; ++r) {
        const size_t row = (size_t)m0 + wr * 64 + mi * 16 + lhi * 4 + r;
        float v = acc[mi][ni][r] + bv;
        if constexpr (F32OUT) __builtin_nontemporal_store(v, &Cf[row * (size_t)N + col]);
        else                  Ch[row * (size_t)N + col] = f2h_bits(v);
      }
    }
  }
}

// ---------------- causal flash attention
// qkv[M, 3072]: cols [0,1024)=Q(h,d), [1024,2048)=K, [2048,3072)=V  (f16)
// one block = one (b,h,qtile of 64 rows); 4 waves x 16 q-rows; KV tiles of 64.
// Vt double-buffered; next V tile prefetched into regs at loop top (T14) and
// written to the other buffer after PV; ONE barrier per KV-tile.
// Causal mask applied ONLY on the diagonal tile (kt==qt, uniform branch).
__global__ __launch_bounds__(256) void attn_kernel(
    const unsigned short* __restrict__ qkv, unsigned short* __restrict__ out) {
  __shared__ unsigned short Vt[2][64 * 72];    // V^T tiles: [d][kv], padded
  __shared__ unsigned short Pl[4 * 16 * 72];   // per-wave P tile: [qrow][kv]
  const int bid = blockIdx.x;
  const int qt = bid & 31, bh = bid >> 5;
  const int b = bh >> 4, h = bh & 15;
  const int tid = threadIdx.x, w = tid >> 6, l = tid & 63;
  const int l15 = l & 15, lhi = l >> 4;
  const int q0 = qt * 64;
  const size_t RS = QKVN;  // row stride in elements
  const unsigned short* qbase = qkv + (size_t)b * TSEQ * RS + h * 64;
  const unsigned short* kbase = qbase + EDIM;
  const unsigned short* vbase = qbase + 2 * EDIM;

  // Q fragments stay in registers for the whole kernel
  f16x8 qa[2];
  {
    const int qrow = q0 + w * 16 + l15;
#pragma unroll
    for (int ks = 0; ks < 2; ++ks)
      qa[ks] = *reinterpret_cast<const f16x8*>(qbase + (size_t)qrow * RS + ks * 32 + lhi * 8);
  }
  // stage V tile 0 into Vt[0]
  const int vr_ = tid >> 3, vc8 = (tid & 7) * 8;
  {
#pragma unroll
    for (int p = 0; p < 2; ++p) {
      const int rr = vr_ + p * 32;
      u16x8v v = *reinterpret_cast<const u16x8v*>(vbase + (size_t)rr * RS + vc8);
#pragma unroll
      for (int j = 0; j < 8; ++j) Vt[0][(vc8 + j) * 72 + rr] = v[j];
    }
  }
  float m_run[4], l_run[4];
  f32x4 o[4] = {};
#pragma unroll
  for (int r = 0; r < 4; ++r) { m_run[r] = -__builtin_inff(); l_run[r] = 0.f; }
  const int myrow = q0 + w * 16 + lhi * 4;
  unsigned short* pl = &Pl[w * 16 * 72];
  __syncthreads();

  for (int kt = 0; kt <= qt; ++kt) {
    const int kv0 = kt * 64;
    // prefetch next V tile into regs (clamped; consumed after PV)
    const int tn = (kt + 1 <= qt) ? (kt + 1) : qt;
    u16x8v vpre[2];
#pragma unroll
    for (int p = 0; p < 2; ++p)
      vpre[p] = *reinterpret_cast<const u16x8v*>(
          vbase + (size_t)(tn * 64 + vr_ + p * 32) * RS + vc8);
    // S = Q K^T  (B-operand = K rows read straight from L2)
    f32x4 s[4];
    __builtin_amdgcn_s_setprio(1);
#pragma unroll
    for (int ct = 0; ct < 4; ++ct) {
      f32x4 acc = {};
#pragma unroll
      for (int ks = 0; ks < 2; ++ks) {
        f16x8 kb = *reinterpret_cast<const f16x8*>(
            kbase + (size_t)(kv0 + ct * 16 + l15) * RS + ks * 32 + lhi * 8);
        acc = __builtin_amdgcn_mfma_f32_16x16x32_f16(qa[ks], kb, acc, 0, 0, 0);
      }
      s[ct] = acc;
    }
    __builtin_amdgcn_s_setprio(0);
    // scale; causal mask only on the diagonal tile (uniform branch)
    if (kt == qt) {
#pragma unroll
      for (int ct = 0; ct < 4; ++ct) {
        const int col = kv0 + ct * 16 + l15;
#pragma unroll
        for (int r = 0; r < 4; ++r) {
          float v = s[ct][r] * 0.125f;
          if (col > myrow + r) v = -__builtin_inff();
          s[ct][r] = v;
        }
      }
    } else {
#pragma unroll
      for (int ct = 0; ct < 4; ++ct)
#pragma unroll
        for (int r = 0; r < 4; ++r) s[ct][r] *= 0.125f;
    }
    // online softmax (rows live across a 16-lane group)
    float alpha[4];
#pragma unroll
    for (int r = 0; r < 4; ++r) {
      float mx = fmaxf(fmaxf(s[0][r], s[1][r]), fmaxf(s[2][r], s[3][r]));
      mx = fmaxf(mx, __shfl_xor(mx, 1)); mx = fmaxf(mx, __shfl_xor(mx, 2));
      mx = fmaxf(mx, __shfl_xor(mx, 4)); mx = fmaxf(mx, __shfl_xor(mx, 8));
      const float mn = fmaxf(m_run[r], mx);
      alpha[r] = __expf(m_run[r] - mn);   // exp(-inf)=0 on first tile
      m_run[r] = mn;
    }
    float rs[4] = {0.f, 0.f, 0.f, 0.f};
#pragma unroll
    for (int ct = 0; ct < 4; ++ct)
#pragma unroll
      for (int r = 0; r < 4; ++r) {
        const float p = __expf(s[ct][r] - m_run[r]);   // masked -> 0
        s[ct][r] = p;
        rs[r] += p;
      }
#pragma unroll
    for (int r = 0; r < 4; ++r) {
      float t = rs[r];
      t += __shfl_xor(t, 1); t += __shfl_xor(t, 2);
      t += __shfl_xor(t, 4); t += __shfl_xor(t, 8);
      l_run[r] = l_run[r] * alpha[r] + t;
    }
#pragma unroll
    for (int ct = 0; ct < 4; ++ct)
#pragma unroll
      for (int r = 0; r < 4; ++r) o[ct][r] *= alpha[r];
    // P (C-layout) -> LDS -> A-layout fragments
#pragma unroll
    for (int ct = 0; ct < 4; ++ct)
#pragma unroll
      for (int r = 0; r < 4; ++r)
        pl[(lhi * 4 + r) * 72 + ct * 16 + l15] = f2h_bits(s[ct][r]);
    // O += P V
    const unsigned short* vt = Vt[kt & 1];
#pragma unroll
    for (int ks = 0; ks < 2; ++ks) {
      f16x8 pa = *reinterpret_cast<const f16x8*>(&pl[l15 * 72 + ks * 32 + lhi * 8]);
      __builtin_amdgcn_s_setprio(1);
#pragma unroll
      for (int ct = 0; ct < 4; ++ct) {
        f16x8 vb = *reinterpret_cast<const f16x8*>(&vt[(ct * 16 + l15) * 72 + ks * 32 + lhi * 8]);
        o[ct] = __builtin_amdgcn_mfma_f32_16x16x32_f16(pa, vb, o[ct], 0, 0, 0);
      }
      __builtin_amdgcn_s_setprio(0);
    }
    // write prefetched V tile into the other buffer (uniform branch)
    if (kt < qt) {
      unsigned short* vtn = Vt[(kt + 1) & 1];
#pragma unroll
      for (int p = 0; p < 2; ++p) {
        const int rr = vr_ + p * 32;
#pragma unroll
        for (int j = 0; j < 8; ++j) vtn[(vc8 + j) * 72 + rr] = vpre[p][j];
      }
    }
    __syncthreads();
  }
  // epilogue: out[b*T + row, h*64 + d] = o / l  (rcp once per row)
  unsigned short* obase = out + ((size_t)(b * TSEQ + q0 + w * 16)) * EDIM + h * 64;
#pragma unroll
  for (int r = 0; r < 4; ++r) {
    const float linv = 1.0f / l_run[r];
#pragma unroll
    for (int ct = 0; ct < 4; ++ct) {
      obase[(size_t)(lhi * 4 + r) * EDIM + ct * 16 + l15] = f2h_bits(o[ct][r] * linv);
    }
  }
}

extern "C" void kernel_launch(void* const* d_in, const int* in_sizes, int n_in,
                              void* d_out, int out_size, void* d_ws, size_t ws_size,
                              hipStream_t stream) {
  const int*   X    = (const int*)d_in[0];
  const float* tokE = (const float*)d_in[1];
  const float* posE = (const float*)d_in[2];
  const float* Wq   = (const float*)d_in[3];
  const float* Wk   = (const float*)d_in[4];
  const float* Wv   = (const float*)d_in[5];
  const float* lmW  = (const float*)d_in[6];
  const float* lmb  = (const float*)d_in[7];
  float* out = (float*)d_out;

  // workspace layout (f16 elements); total ~108.5 MB
  unsigned short* ws   = (unsigned short*)d_ws;
  unsigned short* x    = ws;                              // [4096,1024]
  unsigned short* att  = x    + (size_t)MROWS * EDIM;     // [4096,1024]
  unsigned short* wqkv = att  + (size_t)MROWS * EDIM;     // [3072,1024]
  unsigned short* qkv  = wqkv + (size_t)QKVN * EDIM;      // [4096,3072]
  unsigned short* lmWt = qkv  + (size_t)MROWS * QKVN;     // [32000,1024]

  embed_kernel<<<(MROWS * EDIM / 8) / 256, 256, 0, stream>>>(X, tokE, posE, x);
  trans_qkvw<<<3 * NH * (EDIM / 64), 256, 0, stream>>>(Wq, Wk, Wv, wqkv);
  trans_lmw<<<(VOC / 64) * (EDIM / 64), 256, 0, stream>>>(lmW, lmWt);
  // QKV proj: M=4096, N=3072, K=1024 -> (3072/256)*(4096/128) = 12*32 = 384 blocks
  gemm128<false, false><<<(QKVN / 256) * (MROWS / 128), 512, 0, stream>>>(
      x, wqkv, nullptr, qkv, nullptr, QKVN, EDIM);
  attn_kernel<<<NB * NH * (TSEQ / 64), 256, 0, stream>>>(qkv, att);
  // LM head: M=4096, N=32000, K=1024 -> (32000/256)*(4096/128) = 125*32 = 4000 blocks
  gemm128<true, true><<<(VOC / 256) * (MROWS / 128), 512, 0, stream>>>(
      att, lmWt, out, nullptr, lmb, VOC, EDIM);
}